// Round 15
// baseline (462.502 us; speedup 1.0000x reference)
//
#include <hip/hip_runtime.h>
#include <hip/hip_bf16.h>

using bf16 = __hip_bfloat16;

// Problem constants
constexpr int NQ  = 100;
constexpr int NT  = 197;
constexpr int BSZ = 128;
constexpr int EMB = 768;
constexpr int NHD = 12;
constexpr int HDD = 64;
constexpr int COLS = BSZ * EMB;          // 98304
constexpr int M_Q  = 12800;
constexpr int M_KV = 25216;
constexpr int M_KVP = 25344;             // padded to 99*256 for 256-row tiles
constexpr int TPAD = 224;

// ---- layout (lifetime-packed; 199.5MB < proven 218.4MB budget) ----
constexpr size_t SZ_Q16  = (size_t)M_Q  * EMB * 2;   // 19,660,800
constexpr size_t SZ_KV16 = (size_t)M_KV * EMB * 2;   // 38,731,776
constexpr size_t SZ_KVP  = (size_t)M_KVP * EMB * 2;  // 38,928,384
constexpr size_t SZ_WI   = (size_t)3 * EMB * EMB * 2;// 3,538,944
constexpr size_t SZ_T16  = (size_t)COLS * TPAD * 2;  // 44,040,192
constexpr size_t OFF_QB   = 256;
constexpr size_t OFF_KB   = OFF_QB + SZ_Q16;
constexpr size_t OFF_VB   = OFF_KB + SZ_KV16;
constexpr size_t OFF_WI   = OFF_VB + SZ_KV16;
constexpr size_t OFF_QP16 = OFF_WI + SZ_WI;
constexpr size_t OFF_KP16 = OFF_QP16 + SZ_Q16;
constexpr size_t OFF_VP16 = OFF_KP16 + SZ_KVP;
constexpr size_t OFF_QMNT = OFF_VP16 + SZ_KVP;
constexpr size_t OFF_XMNT = OFF_QMNT + 57344;
constexpr size_t OFF_WO   = OFF_XMNT + 57344;        // end 199,475,456
constexpr size_t OFF_KPT  = 256;                     // over qb+kb
constexpr size_t OFF_VPT  = OFF_KPT + SZ_T16;        // over kb-tail+vb
constexpr size_t OFF_W16T = OFF_VPT + SZ_T16;        // over wi+qp16
constexpr size_t OFF_QNT  = OFF_KP16;                // over kp16 (must run AFTER k_trn2)
constexpr size_t OFF_G16  = OFF_VP16;                // over vp16
constexpr size_t OFF_XO   = 256;                     // over kpT

__device__ __forceinline__ float dl(const float* p) { return *p; }
__device__ __forceinline__ float dl(const bf16* p) { return __bfloat162float(*p); }

__device__ __forceinline__ ushort f2bf(float x) {
    union { float f; unsigned u; } v; v.f = x;
    unsigned r = v.u + 0x7FFFu + ((v.u >> 16) & 1u);   // RNE
    return (ushort)(r >> 16);
}
__device__ __forceinline__ float bf2f(ushort x) {
    union { unsigned u; float f; } v; v.u = (unsigned)x << 16;
    return v.f;
}
__device__ __forceinline__ void dstore(float* p, float v) { *p = v; }
__device__ __forceinline__ void dstore(bf16* p, float v) { *p = __float2bfloat16(v); }

typedef __attribute__((ext_vector_type(8))) short short8;
typedef __attribute__((ext_vector_type(4))) short shortv4;
typedef __attribute__((ext_vector_type(4))) float f32x4;

__device__ __forceinline__ void gload16(const bf16* g, ushort* l) {
    __builtin_amdgcn_global_load_lds(
        (const __attribute__((address_space(1))) unsigned int*)g,
        (__attribute__((address_space(3))) unsigned int*)l, 16, 0, 0);
}

__device__ __forceinline__ int2 xcd_swz(int bx, int by, int gx, int gy) {
    const int nwg = gx * gy;
    const int L = by * gx + bx;
    const int q = nwg >> 3, r = nwg & 7;
    const int c = L & 7, i = L >> 3;
    const int wg = (c < r ? c * (q + 1) : r * (q + 1) + (c - r) * q) + i;
    return make_int2(wg % gx, wg / gx);
}

// ---------- fused 5-segment f32 -> bf16 convert ----------
__global__ __launch_bounds__(256) void k_cvt5(
        const float* __restrict__ s0, bf16* __restrict__ d0,   // wi   864 blocks
        const float* __restrict__ s1, bf16* __restrict__ d1,   // qb   4800
        const float* __restrict__ s2, bf16* __restrict__ d2,   // kb   9456
        const float* __restrict__ s3, bf16* __restrict__ d3,   // vb   9456
        const float* __restrict__ s4, bf16* __restrict__ d4) { // wo   288
    int bk = blockIdx.x;
    const float* s; bf16* d; int lb;
    if      (bk < 864)   { s = s0; d = d0; lb = bk; }
    else if (bk < 5664)  { s = s1; d = d1; lb = bk - 864; }
    else if (bk < 15120) { s = s2; d = d2; lb = bk - 5664; }
    else if (bk < 24576) { s = s3; d = d3; lb = bk - 15120; }
    else                 { s = s4; d = d4; lb = bk - 24576; }
    size_t i = ((size_t)lb * 256 + threadIdx.x) * 8;
    float4 a = *(const float4*)(s + i), b = *(const float4*)(s + i + 4);
    short8 r;
    r[0] = (short)f2bf(a.x); r[1] = (short)f2bf(a.y); r[2] = (short)f2bf(a.z); r[3] = (short)f2bf(a.w);
    r[4] = (short)f2bf(b.x); r[5] = (short)f2bf(b.y); r[6] = (short)f2bf(b.z); r[7] = (short)f2bf(b.w);
    *(short8*)(d + i) = r;
}

// ---------- MERGED mapper normalizations (round-14 proven) ----------
template <typename T>
__global__ __launch_bounds__(256) void k_maps(const T* __restrict__ qm, bf16* qmnT,
                                              const T* __restrict__ xm, bf16* xmnT) {
    __shared__ float red[256];
    const int bk = blockIdx.x, tid = threadIdx.x;
    if (bk < 224) {
        int t = bk;
        float v = (t < NT && tid < NQ) ? dl(&qm[t * NQ + tid]) : 0.f;
        if (tid < 128) red[tid] = v * v;
        __syncthreads();
        for (int s = 64; s > 0; s >>= 1) { if (tid < s) red[tid] += red[tid + s]; __syncthreads(); }
        float inv = 1.f / fmaxf(sqrtf(red[0]), 1e-12f);
        if (tid < 128)
            dstore(&qmnT[(size_t)tid * TPAD + t], (t < NT && tid < NQ) ? v * inv : 0.f);
    } else {
        int q = bk - 224, t = tid;
        float v = (q < NQ && t < NT) ? dl(&xm[q * NT + t]) : 0.f;
        red[t] = v * v;
        __syncthreads();
        for (int s = 128; s > 0; s >>= 1) { if (t < s) red[t] += red[t + s]; __syncthreads(); }
        float inv = 1.f / fmaxf(sqrtf(red[0]), 1e-12f);
        if (t < TPAD) dstore(&xmnT[(size_t)q * TPAD + t], (q < NQ && t < NT) ? v * inv : 0.f);
    }
}

// ---------- transpose (+ optional column L2-norm) ----------
template <int NR, int TP, int NORM>
__global__ __launch_bounds__(256) void k_trn(const bf16* __restrict__ src,
        bf16* __restrict__ dst) {
    __shared__ ushort tile[TP * 73];
    __shared__ float ssp[4][64];
    __shared__ float inv_s[64];
    const int col0 = blockIdx.x * 64;
    const int tid = threadIdx.x;
    const int c = tid & 63, tb = tid >> 6;
    float ss = 0.f;
#pragma unroll
    for (int it = 0; it < TP / 4; ++it) {
        int t = tb + it * 4;
        ushort v = 0;
        if (t < NR) v = *(const ushort*)&src[(size_t)t * COLS + col0 + c];
        tile[t * 73 + c] = v;
        if (NORM) { float f = bf2f(v); ss = fmaf(f, f, ss); }
    }
    if (NORM) {
        ssp[tb][c] = ss;
        __syncthreads();
        if (tid < 64) {
            float s = ssp[0][tid] + ssp[1][tid] + ssp[2][tid] + ssp[3][tid];
            inv_s[tid] = 1.f / fmaxf(sqrtf(s), 1e-12f);
        }
    }
    __syncthreads();
    constexpr int UPC = TP / 8;
#pragma unroll
    for (int it = 0; it < (64 * UPC) / 256; ++it) {
        int u = tid + it * 256;
        int cc = u / UPC, t0 = (u % UPC) * 8;
        float inv = NORM ? inv_s[cc] : 1.f;
        short8 s;
#pragma unroll
        for (int r = 0; r < 8; ++r) {
            ushort raw = tile[(t0 + r) * 73 + cc];
            s[r] = NORM ? (short)f2bf(bf2f(raw) * inv) : (short)raw;
        }
        *(short8*)&dst[(size_t)(col0 + cc) * TP + t0] = s;
    }
}

// ---------- fused dual transpose: kp16->kpT16(norm) + vp16->vpT16(plain) ----------
__global__ __launch_bounds__(256) void k_trn2(const bf16* __restrict__ kp,
        const bf16* __restrict__ vp, bf16* __restrict__ kpT, bf16* __restrict__ vpT) {
    __shared__ ushort tile[TPAD * 73];
    __shared__ float ssp[4][64];
    __shared__ float inv_s[64];
    const int bk = blockIdx.x;
    const bool vseg = bk >= 1536;
    const bf16* src = vseg ? vp : kp;
    bf16* dst = vseg ? vpT : kpT;
    const int col0 = (vseg ? bk - 1536 : bk) * 64;
    const int tid = threadIdx.x;
    const int c = tid & 63, tb = tid >> 6;
    float ss = 0.f;
#pragma unroll
    for (int it = 0; it < TPAD / 4; ++it) {
        int t = tb + it * 4;
        ushort v = 0;
        if (t < NT) v = *(const ushort*)&src[(size_t)t * COLS + col0 + c];
        tile[t * 73 + c] = v;
        if (!vseg) { float f = bf2f(v); ss = fmaf(f, f, ss); }
    }
    if (!vseg) {
        ssp[tb][c] = ss;
        __syncthreads();
        if (tid < 64) {
            float s = ssp[0][tid] + ssp[1][tid] + ssp[2][tid] + ssp[3][tid];
            inv_s[tid] = 1.f / fmaxf(sqrtf(s), 1e-12f);
        }
    }
    __syncthreads();
    constexpr int UPC = TPAD / 8;                 // 28
#pragma unroll
    for (int it = 0; it < (64 * UPC) / 256; ++it) {   // 7
        int u = tid + it * 256;
        int cc = u / UPC, t0 = (u % UPC) * 8;
        float inv = vseg ? 1.f : inv_s[cc];
        short8 s;
#pragma unroll
        for (int r = 0; r < 8; ++r) {
            ushort raw = tile[(t0 + r) * 73 + cc];
            s[r] = vseg ? (short)raw : (short)f2bf(bf2f(raw) * inv);
        }
        *(short8*)&dst[(size_t)(col0 + cc) * TPAD + t0] = s;
    }
}

// ===== k_mm9: 256x128 MFMA GEMM, BK=32, 2 blocks/CU (occupancy-shaped) ====
// 8 waves of 64x64 wave-tiles (wr=wid>>1 in 0..3 m, wc=wid&1 in 0..1 n).
// acc[4][4] = 64 regs/wave; LDS 48KB (A 2x16KB, B 2x8KB) -> 2 blocks/CU at
// 4 waves/SIMD. Edge ledger identical in kind to proven mm8:
//   E1: LGK0+BAR after last ds_read of buf c, before restaging c.
//   E2: VM3/VM0+BAR -> tile t+1 published.
// Swizzle (64B rows, 4x16B slots): phys = logical ^ (row&3); source pre-swz
// (tid&3)^((tid>>2)&3) (involution, rule #21). Per-tile MFMAs share one
// k-slice; tiles ascend k -> accumulation order bit-identical.
#define MM9_BAR  { __builtin_amdgcn_s_barrier(); __builtin_amdgcn_sched_barrier(0); }
#define MM9_LGK0 { asm volatile("s_waitcnt lgkmcnt(0)" ::: "memory"); __builtin_amdgcn_sched_barrier(0); }
#define MM9_VM3  { asm volatile("s_waitcnt vmcnt(3)" ::: "memory"); __builtin_amdgcn_sched_barrier(0); }
#define MM9_VM0  { asm volatile("s_waitcnt vmcnt(0)" ::: "memory"); __builtin_amdgcn_sched_barrier(0); }
// A half H (rows H*128..+127) of K-tile KT -> buffer CUR (1 gload, 512 lanes x 16B)
#define MM9_STAGE_A(CUR, H, KT) do { \
    const bf16* gb_ = Ab + (size_t)(m0 + (H)*128 + (tid >> 2)) * EMB + (KT)*32 + sk_sw; \
    gload16(gb_, A_lds + (CUR)*8192 + (H)*4096 + wid*512); \
} while (0)
// B tile (128 rows) of K-tile KT -> buffer CUR (1 gload)
#define MM9_STAGE_B(CUR, KT) do { \
    const bf16* gb_ = Wb + (size_t)(n0 + (tid >> 2)) * EMB + (KT)*32 + sk_sw; \
    gload16(gb_, B_lds + (CUR)*4096 + wid*512); \
} while (0)
#define MM9_LOADFRAGS(CUR) { \
    _Pragma("unroll") for (int m_ = 0; m_ < 4; ++m_) { \
        int ra_ = wr*64 + m_*16 + ln15; \
        a[m_] = *(const short8*)&A_lds[(CUR)*8192 + ra_*32 + ((q8 ^ (ra_ & 3)))*8]; } \
    _Pragma("unroll") for (int j_ = 0; j_ < 4; ++j_) { \
        int rb_ = wc*64 + j_*16 + ln15; \
        b[j_] = *(const short8*)&B_lds[(CUR)*4096 + rb_*32 + ((q8 ^ (rb_ & 3)))*8]; } }
#define MM9_QUAD(MB) { \
    __builtin_amdgcn_s_setprio(1); \
    _Pragma("unroll") for (int m_ = 0; m_ < 2; ++m_) \
        _Pragma("unroll") for (int j_ = 0; j_ < 4; ++j_) \
            acc[(MB) + m_][j_] = __builtin_amdgcn_mfma_f32_16x16x32_bf16( \
                a[(MB) + m_], b[j_], acc[(MB) + m_][j_], 0, 0, 0); \
    __builtin_amdgcn_s_setprio(0); }

__global__ __launch_bounds__(512, 4) void k_mm9(
        const bf16* __restrict__ A0, const bf16* __restrict__ A1, const bf16* __restrict__ A2,
        const bf16* __restrict__ W,
        bf16* __restrict__ C0, bf16* __restrict__ C1, bf16* __restrict__ C2,
        const float* __restrict__ bias, int mt0, int mt01) {
    __shared__ __align__(16) ushort A_lds[2 * 8192];   // 32KB
    __shared__ __align__(16) ushort B_lds[2 * 4096];   // 16KB
    const int tid = threadIdx.x;
    const int2 bxy = xcd_swz(blockIdx.x, blockIdx.y, gridDim.x, gridDim.y);
    int seg = 0, lby = bxy.y;
    if (bxy.y < mt0)       { seg = 0; lby = bxy.y; }
    else if (bxy.y < mt01) { seg = 1; lby = bxy.y - mt0; }
    else                   { seg = 2; lby = bxy.y - mt01; }
    const bf16* Ab = seg == 0 ? A0 : (seg == 1 ? A1 : A2);
    const bf16* Wb = W + (size_t)seg * EMB * EMB;
    bf16* C = seg == 0 ? C0 : (seg == 1 ? C1 : C2);
    const float* bp = bias + seg * EMB;
    const int m0 = lby * 256, n0 = bxy.x * 128;
    const int wid = tid >> 6, ln = tid & 63;
    const int wr = wid >> 1, wc = wid & 1;
    const int ln15 = ln & 15, q8 = ln >> 4;
    const int sk_sw = (((tid & 3) ^ ((tid >> 2) & 3)) * 8);   // pre-swz source col

    f32x4 acc[4][4] = {};
    short8 a[4], b[4];

    // prologue: tiles 0,1 staged (3 gloads each); tile0 published
    MM9_STAGE_A(0, 0, 0); MM9_STAGE_A(0, 1, 0); MM9_STAGE_B(0, 0);
    MM9_STAGE_A(1, 0, 1); MM9_STAGE_A(1, 1, 1); MM9_STAGE_B(1, 1);
    MM9_VM3;
    MM9_BAR;

    // main loop: 24 K-tiles (K=768, BK=32)
    for (int t = 0; t < 24; ++t) {
        const int c = t & 1, nxt = t + 2;
        MM9_LOADFRAGS(c);         // 8 ds_reads (all reads of buf c this iter)
        MM9_QUAD(0);              // m0,m1 -> 8 MFMA
        MM9_LGK0;                 // reads serviced for this wave
        MM9_BAR;                  // E1: for all waves -> restage safe
        if (nxt < 24) { MM9_STAGE_A(c, 0, nxt); MM9_STAGE_A(c, 1, nxt); MM9_STAGE_B(c, nxt); }
        if (t < 22) { MM9_VM3; } else { MM9_VM0; }   // tile t+1 landed
        MM9_QUAD(2);              // m2,m3 -> 8 MFMA
        MM9_BAR;                  // E2: t+1 published
    }

    // epilogue: C-write with bias
#pragma unroll
    for (int j = 0; j < 4; ++j) {
        const int n = n0 + wc * 64 + j * 16 + ln15;
        const float bv = bp[n];
#pragma unroll
        for (int m = 0; m < 4; ++m) {
            const int mb = m0 + wr * 64 + m * 16 + q8 * 4;
#pragma unroll
            for (int r = 0; r < 4; ++r)
                dstore(&C[(size_t)(mb + r) * EMB + n], acc[m][j][r] + bv);
        }
    }
}

// ---------- 2-phase fused projection (bf16 hedge path; round-9 proven) ----------
template <typename TBias>
__global__ __launch_bounds__(256) void k_proj2(
        const bf16* __restrict__ Aq, const bf16* __restrict__ Ak, const bf16* __restrict__ Av,
        const bf16* __restrict__ Wi, bf16* __restrict__ Cq, bf16* __restrict__ Ck,
        bf16* __restrict__ Cv, const TBias* __restrict__ bias) {
    __shared__ __align__(16) ushort As[128 * 32];
    __shared__ __align__(16) ushort Bs[128 * 32];
    const int t = threadIdx.x;
    const int2 bxy = xcd_swz(blockIdx.x, blockIdx.y, gridDim.x, gridDim.y);
    int byy = bxy.y, seg, lby;
    if (byy < 100)      { seg = 0; lby = byy; }
    else if (byy < 297) { seg = 1; lby = byy - 100; }
    else                { seg = 2; lby = byy - 297; }
    const bf16* Ab = seg == 0 ? Aq : (seg == 1 ? Ak : Av);
    const bf16* Wb = Wi + (size_t)seg * EMB * EMB;
    bf16* C = seg == 0 ? Cq : (seg == 1 ? Ck : Cv);
    const TBias* bp = bias + seg * EMB;
    const int n0 = bxy.x * 128, m0 = lby * 128;
    const int ln = t & 63, wv = t >> 6;
    const int ln15 = ln & 15, q8 = ln >> 4;
    const int mw = (wv & 1) * 64, nw = (wv >> 1) * 64;
    const int sr = ln >> 2, sk = (ln & 3) * 8;
    const bf16* gA = Ab + (size_t)(m0 + wv * 32 + sr) * EMB + sk;
    const bf16* gB = Wb + (size_t)(n0 + wv * 32 + sr) * EMB + sk;
    const size_t r16 = (size_t)16 * EMB;
    ushort* lA = &As[wv * 1024];
    ushort* lB = &Bs[wv * 1024];
    f32x4 acc[4][4] = {};
    for (int k0 = 0; k0 < EMB; k0 += 32) {
        gload16(gA + k0,       lA);
        gload16(gA + r16 + k0, lA + 512);
        gload16(gB + k0,       lB);
        gload16(gB + r16 + k0, lB + 512);
        __syncthreads();
        short8 a[4], b[4];
#pragma unroll
        for (int i = 0; i < 4; ++i)
            a[i] = *(const short8*)&As[(mw + i * 16 + ln15) * 32 + q8 * 8];
#pragma unroll
        for (int j = 0; j < 4; ++j)
            b[j] = *(const short8*)&Bs[(nw + j * 16 + ln15) * 32 + q8 * 8];
#pragma unroll
        for (int i = 0; i < 4; ++i)
#pragma unroll
            for (int j = 0; j < 4; ++j)
                acc[i][j] = __builtin_amdgcn_mfma_f32_16x16x32_bf16(a[i], b[j], acc[i][j], 0, 0, 0);
        __syncthreads();
    }
#pragma unroll
    for (int j = 0; j < 4; ++j) {
        const int n = n0 + nw + j * 16 + ln15;
        const float bv = dl(&bp[n]);
#pragma unroll
        for (int i = 0; i < 4; ++i) {
            const int mb = m0 + mw + i * 16 + q8 * 4;
#pragma unroll
            for (int r = 0; r < 4; ++r)
                dstore(&C[(size_t)(mb + r) * EMB + n], acc[i][j][r] + bv);
        }
    }
}

// ---------- FUSED mapper GEMM: g16 | w16T (K=224; round-9 proven) ----------
__global__ __launch_bounds__(256) void k_gw(
        const bf16* __restrict__ kpT, const bf16* __restrict__ vpT,
        const bf16* __restrict__ qmnT, const bf16* __restrict__ xmnT,
        bf16* __restrict__ g16, bf16* __restrict__ w16T) {
    __shared__ __align__(16) ushort As[128 * 32];
    __shared__ __align__(16) ushort Bs[128 * 32];
    const int t = threadIdx.x;
    const int2 bxy = xcd_swz(blockIdx.x, blockIdx.y, gridDim.x, gridDim.y);
    const bool wseg = bxy.y >= 768;
    const int lby = wseg ? bxy.y - 768 : bxy.y;
    const bf16* Ab = wseg ? vpT : kpT;
    const bf16* Bb = wseg ? xmnT : qmnT;
    const int m0 = lby * 128;
    const int ln = t & 63, wv = t >> 6;
    const int ln15 = ln & 15, q8 = ln >> 4;
    const int mw = (wv & 1) * 64, nw = (wv >> 1) * 64;
    const int sr = ln >> 2, sk = (ln & 3) * 8;
    const bf16* gA = Ab + (size_t)(m0 + wv * 32 + sr) * TPAD + sk;
    const bf16* gB = Bb + (size_t)(wv * 32 + sr) * TPAD + sk;
    const size_t r16 = (size_t)16 * TPAD;
    ushort* lA = &As[wv * 1024];
    ushort* lB = &Bs[wv * 1024];
    f32x4 acc[4][4] = {};
    for (int k0 = 0; k0 < TPAD; k0 += 32) {
        gload16(gA + k0,       lA);
        gload16(gA + r16 + k0, lA + 512);
        gload16(gB + k0,       lB);
        gload16(gB + r16 + k0, lB + 512);
        __syncthreads();
        short8 a[4], b[4];
#pragma unroll
        for (int i = 0; i < 4; ++i)
            a[i] = *(const short8*)&As[(mw + i * 16 + ln15) * 32 + q8 * 8];
#pragma unroll
        for (int j = 0; j < 4; ++j)
            b[j] = *(const short8*)&Bs[(nw + j * 16 + ln15) * 32 + q8 * 8];
#pragma unroll
        for (int i = 0; i < 4; ++i)
#pragma unroll
            for (int j = 0; j < 4; ++j)
                acc[i][j] = __builtin_amdgcn_mfma_f32_16x16x32_bf16(a[i], b[j], acc[i][j], 0, 0, 0);
        __syncthreads();
    }
#pragma unroll
    for (int j = 0; j < 4; ++j) {
        const int n = nw + j * 16 + ln15;
#pragma unroll
        for (int i = 0; i < 4; ++i) {
            const int mb = m0 + mw + i * 16 + q8 * 4;
            if (wseg) {
                shortv4 s;
#pragma unroll
                for (int r = 0; r < 4; ++r) s[r] = (short)f2bf(acc[i][j][r]);
                *(shortv4*)&w16T[(size_t)n * COLS + mb] = s;
            } else {
#pragma unroll
                for (int r = 0; r < 4; ++r)
                    dstore(&g16[(size_t)(mb + r) * 128 + n], acc[i][j][r]);
            }
        }
    }
}

// ---------- MFMA bf16 GEMM (out-projection; round-8 proven) ----------
template <typename TC, typename TBias>
__global__ __launch_bounds__(256) void k_gemm_mfma(
        const bf16* __restrict__ Ab, const bf16* __restrict__ Wb,
        TC* __restrict__ C, const TBias* __restrict__ bias,
        int M, int N, int K, int ldc) {
    __shared__ __align__(16) ushort As[128 * 32];
    __shared__ __align__(16) ushort Bs[128 * 32];
    const int t = threadIdx.x;
    const int2 bxy = xcd_swz(blockIdx.x, blockIdx.y, gridDim.x, gridDim.y);
    const int n0 = bxy.x * 128, m0 = bxy.y * 128;
    const int ln = t & 63, wv = t >> 6;
    const int ln15 = ln & 15, q8 = ln >> 4;
    const int mw = (wv & 1) * 64, nw = (wv >> 1) * 64;
    const int sr = ln >> 2, sk = (ln & 3) * 8;
    const bf16* gA = Ab + (size_t)(m0 + wv * 32 + sr) * K + sk;
    const bf16* gB = Wb + (size_t)(n0 + wv * 32 + sr) * K + sk;
    const size_t r16 = (size_t)16 * K;
    ushort* lA = &As[wv * 1024];
    ushort* lB = &Bs[wv * 1024];
    f32x4 acc[4][4] = {};
    for (int k0 = 0; k0 < K; k0 += 32) {
        gload16(gA + k0,       lA);
        gload16(gA + r16 + k0, lA + 512);
        gload16(gB + k0,       lB);
        gload16(gB + r16 + k0, lB + 512);
        __syncthreads();
        short8 a[4], b[4];
#pragma unroll
        for (int i = 0; i < 4; ++i)
            a[i] = *(const short8*)&As[(mw + i * 16 + ln15) * 32 + q8 * 8];
#pragma unroll
        for (int j = 0; j < 4; ++j)
            b[j] = *(const short8*)&Bs[(nw + j * 16 + ln15) * 32 + q8 * 8];
#pragma unroll
        for (int i = 0; i < 4; ++i)
#pragma unroll
            for (int j = 0; j < 4; ++j)
                acc[i][j] = __builtin_amdgcn_mfma_f32_16x16x32_bf16(a[i], b[j], acc[i][j], 0, 0, 0);
        __syncthreads();
    }
#pragma unroll
    for (int j = 0; j < 4; ++j) {
        const int n = n0 + nw + j * 16 + ln15;
        const float bv = dl(&bias[n]);
#pragma unroll
        for (int i = 0; i < 4; ++i) {
            const int mb = m0 + mw + i * 16 + q8 * 4;
#pragma unroll
            for (int r = 0; r < 4; ++r)
                dstore(&C[(size_t)(mb + r) * ldc + n], acc[i][j][r] + bv);
        }
    }
}

// ---------- per-(b,h) attention: MFMA + T14 early w16T load (round-13 proven) ----------
template <typename T>
__global__ __launch_bounds__(256) void k_attn(
        const bf16* __restrict__ qnT, const bf16* __restrict__ g16,
        const bf16* __restrict__ w16T, const T* __restrict__ temp,
        bf16* __restrict__ xo) {
    const int h = blockIdx.x, b = blockIdx.y;
    const int tid = threadIdx.x;
    const int ln = tid & 63, wv = tid >> 6;
    const int ln15 = ln & 15, q8 = ln >> 4;
    const int colbase = b * EMB + h * HDD;
    __shared__ __align__(16) ushort smem[16384];   // 32 KB
    char* sm = (char*)smem;

    short8 wreg[4];
#pragma unroll
    for (int it = 0; it < 4; ++it) {
        int u = tid + it * 256;
        int q = u >> 3, e0 = (u & 7) * 8;
        wreg[it] = *(const short8*)&w16T[(size_t)q * COLS + colbase + e0];
    }

#pragma unroll
    for (int it = 0; it < 4; ++it) {
        int u = tid + it * 256;
        int e = u >> 4, q0 = (u & 15) * 8;
        short8 s = *(const short8*)&g16[(size_t)(colbase + e) * 128 + q0];
        *(short8*)(sm + ((e * 256 + q0 * 2) ^ ((e & 7) << 4))) = s;
    }
#pragma unroll
    for (int it = 0; it < 4; ++it) {
        int u = tid + it * 256;
        int d = u >> 4, q0 = (u & 15) * 8;
        short8 s = *(const short8*)&qnT[(size_t)(colbase + d) * 128 + q0];
        *(short8*)(sm + 16384 + ((d * 256 + q0 * 2) ^ ((d & 7) << 4))) = s;
    }
    __syncthreads();

    const int drow = 16 * wv + ln15;
    f32x4 acc[4] = {};
#pragma unroll
    for (int ks = 0; ks < 4; ++ks) {
        short8 bfrag = *(const short8*)(sm + 16384 +
            ((drow * 256 + ks * 64 + q8 * 16) ^ ((drow & 7) << 4)));
#pragma unroll
        for (int i = 0; i < 4; ++i) {
            int erow = i * 16 + ln15;
            short8 afrag = *(const short8*)(sm +
                ((erow * 256 + ks * 64 + q8 * 16) ^ ((erow & 7) << 4)));
            acc[i] = __builtin_amdgcn_mfma_f32_16x16x32_bf16(afrag, bfrag, acc[i], 0, 0, 0);
        }
    }

    const float tv = dl(&temp[h]);
    float p[4][4];
    float mx = -1e30f;
#pragma unroll
    for (int i = 0; i < 4; ++i)
#pragma unroll
        for (int r = 0; r < 4; ++r) { p[i][r] = acc[i][r] * tv; mx = fmaxf(mx, p[i][r]); }
    mx = fmaxf(mx, __shfl_xor(mx, 16, 64));
    mx = fmaxf(mx, __shfl_xor(mx, 32, 64));
    float sum = 0.f;
#pragma unroll
    for (int i = 0; i < 4; ++i)
#pragma unroll
        for (int r = 0; r < 4; ++r) { p[i][r] = __expf(p[i][r] - mx); sum += p[i][r]; }
    sum += __shfl_xor(sum, 16, 64);
    sum += __shfl_xor(sum, 32, 64);
    const float rs = 1.f / sum;

    __syncthreads();

#pragma unroll
    for (int i = 0; i < 4; ++i) {
        shortv4 s4;
#pragma unroll
        for (int r = 0; r < 4; ++r) s4[r] = (short)f2bf(p[i][r] * rs);
        *(shortv4*)(sm + 16384 + drow * 144 + q8 * 8 + 32 * i) = s4;
    }
#pragma unroll
    for (int it = 0; it < 4; ++it) {
        int u = tid + it * 256;
        int q = u >> 3, e0 = (u & 7) * 8;
        *(short8*)(sm + ((q * 128 + e0 * 2) ^ ((q & 7) << 4))) = wreg[it];
    }
    __syncthreads();

    f32x4 o[7] = {};
#pragma unroll
    for (int ks = 0; ks < 2; ++ks) {
        short8 afrag = *(const short8*)(sm + 16384 + drow * 144 + ks * 64 + q8 * 16);
#pragma unroll
        for (int j = 0; j < 7; ++j) {
            int qrow = j * 16 + ln15;
            short8 bfrag = *(const short8*)(sm +
                ((qrow * 128 + ks * 64 + q8 * 16) ^ ((qrow & 7) << 4)));
            o[j] = __builtin_amdgcn_mfma_f32_16x16x32_bf16(afrag, bfrag, o[j], 0, 0, 0);
        }
    }
    const int dbase = h * HDD + 16 * wv + q8 * 4;
#pragma unroll
    for (int j = 0; j < 7; ++j) {
        int q = j * 16 + ln15;
        if (q < NQ) {
            shortv4 s4;
#pragma unroll
            for (int r = 0; r < 4; ++r) s4[r] = (short)f2bf(o[j][r]);
            *(shortv4*)&xo[(size_t)(q * BSZ + b) * EMB + dbase] = s4;
        }
    }
}

extern "C" void kernel_launch(void* const* d_in, const int* in_sizes, int n_in,
                              void* d_out, int out_size, void* d_ws, size_t ws_size,
                              hipStream_t stream) {
    char* ws = (char*)d_ws;
    bf16* qb16  = (bf16*)(ws + OFF_QB);
    bf16* kb16  = (bf16*)(ws + OFF_KB);
    bf16* vb16  = (bf16*)(ws + OFF_VB);
    bf16* wi16  = (bf16*)(ws + OFF_WI);
    bf16* qp16  = (bf16*)(ws + OFF_QP16);
    bf16* kp16  = (bf16*)(ws + OFF_KP16);
    bf16* vp16  = (bf16*)(ws + OFF_VP16);
    bf16* qmnT  = (bf16*)(ws + OFF_QMNT);
    bf16* xmnT  = (bf16*)(ws + OFF_XMNT);
    bf16* wo16  = (bf16*)(ws + OFF_WO);
    bf16* kpT   = (bf16*)(ws + OFF_KPT);
    bf16* vpT   = (bf16*)(ws + OFF_VPT);
    bf16* w16T  = (bf16*)(ws + OFF_W16T);
    bf16* qnT   = (bf16*)(ws + OFF_QNT);
    bf16* g16   = (bf16*)(ws + OFF_G16);
    bf16* xo16  = (bf16*)(ws + OFF_XO);

    // Host-side dtype detect: query = 9,830,400 elems; bf16 iff 19,660,800 bytes.
    const bool isbf = (in_sizes[0] == 19660800);

    if (isbf) {
        k_maps<bf16><<<352, 256, 0, stream>>>((const bf16*)d_in[8], qmnT,
                                              (const bf16*)d_in[9], xmnT);
        k_proj2<bf16><<<dim3(6, 494), 256, 0, stream>>>(
            (const bf16*)d_in[0], (const bf16*)d_in[1], (const bf16*)d_in[2],
            (const bf16*)d_in[3], qp16, kp16, vp16, (const bf16*)d_in[4]);
        k_trn2<<<3072, 256, 0, stream>>>(kp16, vp16, kpT, vpT);
        k_trn<NQ, 128, 1><<<COLS / 64, 256, 0, stream>>>(qp16, qnT);
        k_gw<<<dim3(1, 1536), 256, 0, stream>>>(kpT, vpT, qmnT, xmnT, g16, w16T);
        k_attn<bf16><<<dim3(NHD, BSZ), 256, 0, stream>>>(
            qnT, g16, w16T, (const bf16*)d_in[7], xo16);
        k_gemm_mfma<bf16, bf16><<<dim3(6, 100), 256, 0, stream>>>(
            xo16, (const bf16*)d_in[5], (bf16*)d_out, (const bf16*)d_in[6],
            M_Q, EMB, EMB, EMB);
    } else {
        k_maps<float><<<352, 256, 0, stream>>>((const float*)d_in[8], qmnT,
                                               (const float*)d_in[9], xmnT);
        // fused one-time conversions: wi | qb | kb | vb | wo
        k_cvt5<<<24864, 256, 0, stream>>>(
            (const float*)d_in[3], wi16,
            (const float*)d_in[0], qb16,
            (const float*)d_in[1], kb16,
            (const float*)d_in[2], vb16,
            (const float*)d_in[5], wo16);
        // occupancy-shaped 256x128 fused projections: qp (50) | kp (99) | vp (99)
        k_mm9<<<dim3(6, 248), 512, 0, stream>>>(
            qb16, kb16, vb16, wi16, qp16, kp16, vp16,
            (const float*)d_in[4], 50, 149);
        // fused transposes: kpT(norm) + vpT
        k_trn2<<<3072, 256, 0, stream>>>(kp16, vp16, kpT, vpT);
        // qnT (kp16 dead; MUST run after k_trn2 — qnT aliases kp16)
        k_trn<NQ, 128, 1><<<COLS / 64, 256, 0, stream>>>(qp16, qnT);
        // fused mapper GEMMs: g16 + w16T
        k_gw<<<dim3(1, 1536), 256, 0, stream>>>(kpT, vpT, qmnT, xmnT, g16, w16T);
        // attention -> xo16 (kpT dead)
        k_attn<float><<<dim3(NHD, BSZ), 256, 0, stream>>>(
            qnT, g16, w16T, (const float*)d_in[7], xo16);
        // out = xo @ wout^T + bout (2-phase proven, f32 C)
        k_gemm_mfma<float, float><<<dim3(6, 100), 256, 0, stream>>>(
            xo16, wo16, (float*)d_out, (const float*)d_in[6], M_Q, EMB, EMB, EMB);
    }
}

// Round 16
// 454.352 us; speedup vs baseline: 1.0179x; 1.0179x over previous
//
#include <hip/hip_runtime.h>
#include <hip/hip_bf16.h>

using bf16 = __hip_bfloat16;

// Problem constants
constexpr int NQ  = 100;
constexpr int NT  = 197;
constexpr int BSZ = 128;
constexpr int EMB = 768;
constexpr int NHD = 12;
constexpr int HDD = 64;
constexpr int COLS = BSZ * EMB;          // 98304
constexpr int M_Q  = 12800;
constexpr int M_KV = 25216;
constexpr int M_KVP = 25344;             // padded to 99*256 for 256-row tiles
constexpr int TPAD = 224;

// ---- layout (lifetime-packed; 199.5MB < proven 218.4MB budget) ----
constexpr size_t SZ_Q16  = (size_t)M_Q  * EMB * 2;   // 19,660,800
constexpr size_t SZ_KV16 = (size_t)M_KV * EMB * 2;   // 38,731,776
constexpr size_t SZ_KVP  = (size_t)M_KVP * EMB * 2;  // 38,928,384
constexpr size_t SZ_WI   = (size_t)3 * EMB * EMB * 2;// 3,538,944
constexpr size_t SZ_T16  = (size_t)COLS * TPAD * 2;  // 44,040,192
constexpr size_t OFF_QB   = 256;
constexpr size_t OFF_KB   = OFF_QB + SZ_Q16;
constexpr size_t OFF_VB   = OFF_KB + SZ_KV16;
constexpr size_t OFF_WI   = OFF_VB + SZ_KV16;
constexpr size_t OFF_QP16 = OFF_WI + SZ_WI;
constexpr size_t OFF_KP16 = OFF_QP16 + SZ_Q16;
constexpr size_t OFF_VP16 = OFF_KP16 + SZ_KVP;
constexpr size_t OFF_QMNT = OFF_VP16 + SZ_KVP;
constexpr size_t OFF_XMNT = OFF_QMNT + 57344;
constexpr size_t OFF_WO   = OFF_XMNT + 57344;        // end 199,475,456
constexpr size_t OFF_KPT  = 256;                     // over qb+kb
constexpr size_t OFF_VPT  = OFF_KPT + SZ_T16;        // over kb-tail+vb
constexpr size_t OFF_W16T = OFF_VPT + SZ_T16;        // over wi+qp16
constexpr size_t OFF_QNT  = OFF_KP16;                // over kp16 (must run AFTER k_trn2)
constexpr size_t OFF_G16  = OFF_VP16;                // over vp16
constexpr size_t OFF_XO   = 256;                     // over kpT

__device__ __forceinline__ float dl(const float* p) { return *p; }
__device__ __forceinline__ float dl(const bf16* p) { return __bfloat162float(*p); }

__device__ __forceinline__ ushort f2bf(float x) {
    union { float f; unsigned u; } v; v.f = x;
    unsigned r = v.u + 0x7FFFu + ((v.u >> 16) & 1u);   // RNE
    return (ushort)(r >> 16);
}
__device__ __forceinline__ float bf2f(ushort x) {
    union { unsigned u; float f; } v; v.u = (unsigned)x << 16;
    return v.f;
}
__device__ __forceinline__ void dstore(float* p, float v) { *p = v; }
__device__ __forceinline__ void dstore(bf16* p, float v) { *p = __float2bfloat16(v); }

typedef __attribute__((ext_vector_type(8))) short short8;
typedef __attribute__((ext_vector_type(4))) short shortv4;
typedef __attribute__((ext_vector_type(4))) float f32x4;

__device__ __forceinline__ void gload16(const bf16* g, ushort* l) {
    __builtin_amdgcn_global_load_lds(
        (const __attribute__((address_space(1))) unsigned int*)g,
        (__attribute__((address_space(3))) unsigned int*)l, 16, 0, 0);
}

__device__ __forceinline__ int2 xcd_swz(int bx, int by, int gx, int gy) {
    const int nwg = gx * gy;
    const int L = by * gx + bx;
    const int q = nwg >> 3, r = nwg & 7;
    const int c = L & 7, i = L >> 3;
    const int wg = (c < r ? c * (q + 1) : r * (q + 1) + (c - r) * q) + i;
    return make_int2(wg % gx, wg / gx);
}

// ---------- fused 5-segment f32 -> bf16 convert ----------
__global__ __launch_bounds__(256) void k_cvt5(
        const float* __restrict__ s0, bf16* __restrict__ d0,   // wi   864 blocks
        const float* __restrict__ s1, bf16* __restrict__ d1,   // qb   4800
        const float* __restrict__ s2, bf16* __restrict__ d2,   // kb   9456
        const float* __restrict__ s3, bf16* __restrict__ d3,   // vb   9456
        const float* __restrict__ s4, bf16* __restrict__ d4) { // wo   288
    int bk = blockIdx.x;
    const float* s; bf16* d; int lb;
    if      (bk < 864)   { s = s0; d = d0; lb = bk; }
    else if (bk < 5664)  { s = s1; d = d1; lb = bk - 864; }
    else if (bk < 15120) { s = s2; d = d2; lb = bk - 5664; }
    else if (bk < 24576) { s = s3; d = d3; lb = bk - 15120; }
    else                 { s = s4; d = d4; lb = bk - 24576; }
    size_t i = ((size_t)lb * 256 + threadIdx.x) * 8;
    float4 a = *(const float4*)(s + i), b = *(const float4*)(s + i + 4);
    short8 r;
    r[0] = (short)f2bf(a.x); r[1] = (short)f2bf(a.y); r[2] = (short)f2bf(a.z); r[3] = (short)f2bf(a.w);
    r[4] = (short)f2bf(b.x); r[5] = (short)f2bf(b.y); r[6] = (short)f2bf(b.z); r[7] = (short)f2bf(b.w);
    *(short8*)(d + i) = r;
}

// ---------- MERGED mapper normalizations (round-14 proven) ----------
template <typename T>
__global__ __launch_bounds__(256) void k_maps(const T* __restrict__ qm, bf16* qmnT,
                                              const T* __restrict__ xm, bf16* xmnT) {
    __shared__ float red[256];
    const int bk = blockIdx.x, tid = threadIdx.x;
    if (bk < 224) {
        int t = bk;
        float v = (t < NT && tid < NQ) ? dl(&qm[t * NQ + tid]) : 0.f;
        if (tid < 128) red[tid] = v * v;
        __syncthreads();
        for (int s = 64; s > 0; s >>= 1) { if (tid < s) red[tid] += red[tid + s]; __syncthreads(); }
        float inv = 1.f / fmaxf(sqrtf(red[0]), 1e-12f);
        if (tid < 128)
            dstore(&qmnT[(size_t)tid * TPAD + t], (t < NT && tid < NQ) ? v * inv : 0.f);
    } else {
        int q = bk - 224, t = tid;
        float v = (q < NQ && t < NT) ? dl(&xm[q * NT + t]) : 0.f;
        red[t] = v * v;
        __syncthreads();
        for (int s = 128; s > 0; s >>= 1) { if (t < s) red[t] += red[t + s]; __syncthreads(); }
        float inv = 1.f / fmaxf(sqrtf(red[0]), 1e-12f);
        if (t < TPAD) dstore(&xmnT[(size_t)q * TPAD + t], (q < NQ && t < NT) ? v * inv : 0.f);
    }
}

// ---------- transpose (+ optional column L2-norm) ----------
template <int NR, int TP, int NORM>
__global__ __launch_bounds__(256) void k_trn(const bf16* __restrict__ src,
        bf16* __restrict__ dst) {
    __shared__ ushort tile[TP * 73];
    __shared__ float ssp[4][64];
    __shared__ float inv_s[64];
    const int col0 = blockIdx.x * 64;
    const int tid = threadIdx.x;
    const int c = tid & 63, tb = tid >> 6;
    float ss = 0.f;
#pragma unroll
    for (int it = 0; it < TP / 4; ++it) {
        int t = tb + it * 4;
        ushort v = 0;
        if (t < NR) v = *(const ushort*)&src[(size_t)t * COLS + col0 + c];
        tile[t * 73 + c] = v;
        if (NORM) { float f = bf2f(v); ss = fmaf(f, f, ss); }
    }
    if (NORM) {
        ssp[tb][c] = ss;
        __syncthreads();
        if (tid < 64) {
            float s = ssp[0][tid] + ssp[1][tid] + ssp[2][tid] + ssp[3][tid];
            inv_s[tid] = 1.f / fmaxf(sqrtf(s), 1e-12f);
        }
    }
    __syncthreads();
    constexpr int UPC = TP / 8;
#pragma unroll
    for (int it = 0; it < (64 * UPC) / 256; ++it) {
        int u = tid + it * 256;
        int cc = u / UPC, t0 = (u % UPC) * 8;
        float inv = NORM ? inv_s[cc] : 1.f;
        short8 s;
#pragma unroll
        for (int r = 0; r < 8; ++r) {
            ushort raw = tile[(t0 + r) * 73 + cc];
            s[r] = NORM ? (short)f2bf(bf2f(raw) * inv) : (short)raw;
        }
        *(short8*)&dst[(size_t)(col0 + cc) * TP + t0] = s;
    }
}

// ---------- fused dual transpose: kp16->kpT16(norm) + vp16->vpT16(plain) ----------
__global__ __launch_bounds__(256) void k_trn2(const bf16* __restrict__ kp,
        const bf16* __restrict__ vp, bf16* __restrict__ kpT, bf16* __restrict__ vpT) {
    __shared__ ushort tile[TPAD * 73];
    __shared__ float ssp[4][64];
    __shared__ float inv_s[64];
    const int bk = blockIdx.x;
    const bool vseg = bk >= 1536;
    const bf16* src = vseg ? vp : kp;
    bf16* dst = vseg ? vpT : kpT;
    const int col0 = (vseg ? bk - 1536 : bk) * 64;
    const int tid = threadIdx.x;
    const int c = tid & 63, tb = tid >> 6;
    float ss = 0.f;
#pragma unroll
    for (int it = 0; it < TPAD / 4; ++it) {
        int t = tb + it * 4;
        ushort v = 0;
        if (t < NT) v = *(const ushort*)&src[(size_t)t * COLS + col0 + c];
        tile[t * 73 + c] = v;
        if (!vseg) { float f = bf2f(v); ss = fmaf(f, f, ss); }
    }
    if (!vseg) {
        ssp[tb][c] = ss;
        __syncthreads();
        if (tid < 64) {
            float s = ssp[0][tid] + ssp[1][tid] + ssp[2][tid] + ssp[3][tid];
            inv_s[tid] = 1.f / fmaxf(sqrtf(s), 1e-12f);
        }
    }
    __syncthreads();
    constexpr int UPC = TPAD / 8;                 // 28
#pragma unroll
    for (int it = 0; it < (64 * UPC) / 256; ++it) {   // 7
        int u = tid + it * 256;
        int cc = u / UPC, t0 = (u % UPC) * 8;
        float inv = vseg ? 1.f : inv_s[cc];
        short8 s;
#pragma unroll
        for (int r = 0; r < 8; ++r) {
            ushort raw = tile[(t0 + r) * 73 + cc];
            s[r] = vseg ? (short)raw : (short)f2bf(bf2f(raw) * inv);
        }
        *(short8*)&dst[(size_t)(col0 + cc) * TPAD + t0] = s;
    }
}

// ===== 256x256 MFMA GEMM: T2-swizzled, minimal-barrier (round-14 proven) ====
// Edges: E1 = LGK0+BAR after last ds_read of buf c (restage safe);
//        E2 = VM8/VM0+BAR (tile t+1 published). Conflicts measured 0.
// TC templated (bf16 intermediates / f32 d_out for the out-projection).
#define MM8_BAR  { __builtin_amdgcn_s_barrier(); __builtin_amdgcn_sched_barrier(0); }
#define MM8_LGK0 { asm volatile("s_waitcnt lgkmcnt(0)" ::: "memory"); __builtin_amdgcn_sched_barrier(0); }
#define MM8_VM8  { asm volatile("s_waitcnt vmcnt(8)" ::: "memory"); __builtin_amdgcn_sched_barrier(0); }
#define MM8_VM0  { asm volatile("s_waitcnt vmcnt(0)" ::: "memory"); __builtin_amdgcn_sched_barrier(0); }
#define MM8_STAGE(CUR, ISB, H, KT) do { \
    const bf16* gb_ = (ISB) ? (Wb + (size_t)(n0 + (H)*128 + srow) * EMB + (KT)*64 + sk_sw) \
                            : (Ab + (size_t)(m0 + (H)*128 + srow) * EMB + (KT)*64 + sk_sw); \
    ushort* lb_ = ((ISB) ? B_lds : A_lds) + (CUR)*16384 + (H)*8192 + wid*512; \
    gload16(gb_, lb_); \
    gload16(gb_ + (size_t)64 * EMB, lb_ + 4096); \
} while (0)
#define MM8_LOADFRAGS(CUR, KK, AARR, BARR) { \
    _Pragma("unroll") for (int m_ = 0; m_ < 8; ++m_) { \
        int ra_ = wr*128 + m_*16 + ln15; \
        AARR[m_] = *(const short8*)&A_lds[(CUR)*16384 + ra_*64 + ((((KK)*4 + q8) ^ (ra_ & 7)))*8]; } \
    _Pragma("unroll") for (int j_ = 0; j_ < 4; ++j_) { \
        int rb_ = wc*64 + j_*16 + ln15; \
        BARR[j_] = *(const short8*)&B_lds[(CUR)*16384 + rb_*64 + ((((KK)*4 + q8) ^ (rb_ & 7)))*8]; } }
#define MM8_QUAD(AARR, BARR, MB) { \
    __builtin_amdgcn_s_setprio(1); \
    _Pragma("unroll") for (int m_ = 0; m_ < 4; ++m_) \
        _Pragma("unroll") for (int j_ = 0; j_ < 4; ++j_) \
            acc[(MB) + m_][j_] = __builtin_amdgcn_mfma_f32_16x16x32_bf16( \
                AARR[(MB) + m_], BARR[j_], acc[(MB) + m_][j_], 0, 0, 0); \
    __builtin_amdgcn_s_setprio(0); }

template <typename TC>
__global__ __launch_bounds__(512, 2) void k_mm8(
        const bf16* __restrict__ A0, const bf16* __restrict__ A1, const bf16* __restrict__ A2,
        const bf16* __restrict__ W,
        TC* __restrict__ C0, TC* __restrict__ C1, TC* __restrict__ C2,
        const float* __restrict__ bias, int mt0, int mt01) {
    __shared__ __align__(16) ushort A_lds[2 * 16384];   // 64KB
    __shared__ __align__(16) ushort B_lds[2 * 16384];   // 64KB
    const int tid = threadIdx.x;
    const int2 bxy = xcd_swz(blockIdx.x, blockIdx.y, gridDim.x, gridDim.y);
    int seg = 0, lby = bxy.y;
    if (bxy.y < mt0)       { seg = 0; lby = bxy.y; }
    else if (bxy.y < mt01) { seg = 1; lby = bxy.y - mt0; }
    else                   { seg = 2; lby = bxy.y - mt01; }
    const bf16* Ab = seg == 0 ? A0 : (seg == 1 ? A1 : A2);
    const bf16* Wb = W + (size_t)seg * EMB * EMB;
    TC* C = seg == 0 ? C0 : (seg == 1 ? C1 : C2);
    const float* bp = bias + seg * EMB;
    const int m0 = lby * 256, n0 = bxy.x * 256;
    const int wid = tid >> 6, ln = tid & 63;
    const int wr = wid >> 2, wc = wid & 3;
    const int ln15 = ln & 15, q8 = ln >> 4;
    const int srow = tid >> 3;
    const int sk_sw = (((tid & 7) ^ (srow & 7)) * 8);   // T2 pre-swizzled source col

    f32x4 acc[8][4] = {};
    short8 a0[8], b0[4], a1[8], b1[4];

    // prologue: tile0 + tile1 staged; tile0 published
    MM8_STAGE(0, 0, 0, 0); MM8_STAGE(0, 0, 1, 0); MM8_STAGE(0, 1, 0, 0); MM8_STAGE(0, 1, 1, 0);
    MM8_STAGE(1, 0, 0, 1); MM8_STAGE(1, 0, 1, 1); MM8_STAGE(1, 1, 0, 1); MM8_STAGE(1, 1, 1, 1);
    MM8_VM8;
    MM8_BAR;

    // main loop: 12 K-tiles, 2 barriers per tile (E1, E2)
    for (int t = 0; t < 12; ++t) {
        const int c = t & 1, nxt = t + 2;
        MM8_LOADFRAGS(c, 0, a0, b0);
        MM8_QUAD(a0, b0, 0);
        MM8_LOADFRAGS(c, 1, a1, b1);
        MM8_QUAD(a0, b0, 4);
        MM8_LGK0;                 // all reads of buf c serviced for this wave
        MM8_BAR;                  // E1: ... for ALL waves -> restage safe
        if (nxt < 12) { MM8_STAGE(c, 0, 0, nxt); MM8_STAGE(c, 0, 1, nxt); }
        MM8_QUAD(a1, b1, 0);
        if (nxt < 12) { MM8_STAGE(c, 1, 0, nxt); MM8_STAGE(c, 1, 1, nxt); }
        if (t < 10) { MM8_VM8; } else { MM8_VM0; }   // own t+1 loads landed
        MM8_QUAD(a1, b1, 4);
        MM8_BAR;                  // E2: t+1 published for all waves
    }

    // epilogue: C-write with bias (same mapping as proven kernel)
#pragma unroll
    for (int j = 0; j < 4; ++j) {
        const int n = n0 + wc * 64 + j * 16 + ln15;
        const float bv = bp[n];
#pragma unroll
        for (int m = 0; m < 8; ++m) {
            const int mb = m0 + wr * 128 + m * 16 + q8 * 4;
#pragma unroll
            for (int r = 0; r < 4; ++r)
                dstore(&C[(size_t)(mb + r) * EMB + n], acc[m][j][r] + bv);
        }
    }
}

// ---------- 2-phase fused projection (bf16 hedge path; round-9 proven) ----------
template <typename TBias>
__global__ __launch_bounds__(256) void k_proj2(
        const bf16* __restrict__ Aq, const bf16* __restrict__ Ak, const bf16* __restrict__ Av,
        const bf16* __restrict__ Wi, bf16* __restrict__ Cq, bf16* __restrict__ Ck,
        bf16* __restrict__ Cv, const TBias* __restrict__ bias) {
    __shared__ __align__(16) ushort As[128 * 32];
    __shared__ __align__(16) ushort Bs[128 * 32];
    const int t = threadIdx.x;
    const int2 bxy = xcd_swz(blockIdx.x, blockIdx.y, gridDim.x, gridDim.y);
    int byy = bxy.y, seg, lby;
    if (byy < 100)      { seg = 0; lby = byy; }
    else if (byy < 297) { seg = 1; lby = byy - 100; }
    else                { seg = 2; lby = byy - 297; }
    const bf16* Ab = seg == 0 ? Aq : (seg == 1 ? Ak : Av);
    const bf16* Wb = Wi + (size_t)seg * EMB * EMB;
    bf16* C = seg == 0 ? Cq : (seg == 1 ? Ck : Cv);
    const TBias* bp = bias + seg * EMB;
    const int n0 = bxy.x * 128, m0 = lby * 128;
    const int ln = t & 63, wv = t >> 6;
    const int ln15 = ln & 15, q8 = ln >> 4;
    const int mw = (wv & 1) * 64, nw = (wv >> 1) * 64;
    const int sr = ln >> 2, sk = (ln & 3) * 8;
    const bf16* gA = Ab + (size_t)(m0 + wv * 32 + sr) * EMB + sk;
    const bf16* gB = Wb + (size_t)(n0 + wv * 32 + sr) * EMB + sk;
    const size_t r16 = (size_t)16 * EMB;
    ushort* lA = &As[wv * 1024];
    ushort* lB = &Bs[wv * 1024];
    f32x4 acc[4][4] = {};
    for (int k0 = 0; k0 < EMB; k0 += 32) {
        gload16(gA + k0,       lA);
        gload16(gA + r16 + k0, lA + 512);
        gload16(gB + k0,       lB);
        gload16(gB + r16 + k0, lB + 512);
        __syncthreads();
        short8 a[4], b[4];
#pragma unroll
        for (int i = 0; i < 4; ++i)
            a[i] = *(const short8*)&As[(mw + i * 16 + ln15) * 32 + q8 * 8];
#pragma unroll
        for (int j = 0; j < 4; ++j)
            b[j] = *(const short8*)&Bs[(nw + j * 16 + ln15) * 32 + q8 * 8];
#pragma unroll
        for (int i = 0; i < 4; ++i)
#pragma unroll
            for (int j = 0; j < 4; ++j)
                acc[i][j] = __builtin_amdgcn_mfma_f32_16x16x32_bf16(a[i], b[j], acc[i][j], 0, 0, 0);
        __syncthreads();
    }
#pragma unroll
    for (int j = 0; j < 4; ++j) {
        const int n = n0 + nw + j * 16 + ln15;
        const float bv = dl(&bp[n]);
#pragma unroll
        for (int i = 0; i < 4; ++i) {
            const int mb = m0 + mw + i * 16 + q8 * 4;
#pragma unroll
            for (int r = 0; r < 4; ++r)
                dstore(&C[(size_t)(mb + r) * EMB + n], acc[i][j][r] + bv);
        }
    }
}

// ---------- FUSED mapper GEMM: g16 | w16T (K=224; round-9 proven) ----------
__global__ __launch_bounds__(256) void k_gw(
        const bf16* __restrict__ kpT, const bf16* __restrict__ vpT,
        const bf16* __restrict__ qmnT, const bf16* __restrict__ xmnT,
        bf16* __restrict__ g16, bf16* __restrict__ w16T) {
    __shared__ __align__(16) ushort As[128 * 32];
    __shared__ __align__(16) ushort Bs[128 * 32];
    const int t = threadIdx.x;
    const int2 bxy = xcd_swz(blockIdx.x, blockIdx.y, gridDim.x, gridDim.y);
    const bool wseg = bxy.y >= 768;
    const int lby = wseg ? bxy.y - 768 : bxy.y;
    const bf16* Ab = wseg ? vpT : kpT;
    const bf16* Bb = wseg ? xmnT : qmnT;
    const int m0 = lby * 128;
    const int ln = t & 63, wv = t >> 6;
    const int ln15 = ln & 15, q8 = ln >> 4;
    const int mw = (wv & 1) * 64, nw = (wv >> 1) * 64;
    const int sr = ln >> 2, sk = (ln & 3) * 8;
    const bf16* gA = Ab + (size_t)(m0 + wv * 32 + sr) * TPAD + sk;
    const bf16* gB = Bb + (size_t)(wv * 32 + sr) * TPAD + sk;
    const size_t r16 = (size_t)16 * TPAD;
    ushort* lA = &As[wv * 1024];
    ushort* lB = &Bs[wv * 1024];
    f32x4 acc[4][4] = {};
    for (int k0 = 0; k0 < TPAD; k0 += 32) {
        gload16(gA + k0,       lA);
        gload16(gA + r16 + k0, lA + 512);
        gload16(gB + k0,       lB);
        gload16(gB + r16 + k0, lB + 512);
        __syncthreads();
        short8 a[4], b[4];
#pragma unroll
        for (int i = 0; i < 4; ++i)
            a[i] = *(const short8*)&As[(mw + i * 16 + ln15) * 32 + q8 * 8];
#pragma unroll
        for (int j = 0; j < 4; ++j)
            b[j] = *(const short8*)&Bs[(nw + j * 16 + ln15) * 32 + q8 * 8];
#pragma unroll
        for (int i = 0; i < 4; ++i)
#pragma unroll
            for (int j = 0; j < 4; ++j)
                acc[i][j] = __builtin_amdgcn_mfma_f32_16x16x32_bf16(a[i], b[j], acc[i][j], 0, 0, 0);
        __syncthreads();
    }
#pragma unroll
    for (int j = 0; j < 4; ++j) {
        const int n = nw + j * 16 + ln15;
#pragma unroll
        for (int i = 0; i < 4; ++i) {
            const int mb = m0 + mw + i * 16 + q8 * 4;
            if (wseg) {
                shortv4 s;
#pragma unroll
                for (int r = 0; r < 4; ++r) s[r] = (short)f2bf(acc[i][j][r]);
                *(shortv4*)&w16T[(size_t)n * COLS + mb] = s;
            } else {
#pragma unroll
                for (int r = 0; r < 4; ++r)
                    dstore(&g16[(size_t)(mb + r) * 128 + n], acc[i][j][r]);
            }
        }
    }
}

// ---------- MFMA bf16 GEMM (bf16-path out-projection; round-8 proven) ----------
template <typename TC, typename TBias>
__global__ __launch_bounds__(256) void k_gemm_mfma(
        const bf16* __restrict__ Ab, const bf16* __restrict__ Wb,
        TC* __restrict__ C, const TBias* __restrict__ bias,
        int M, int N, int K, int ldc) {
    __shared__ __align__(16) ushort As[128 * 32];
    __shared__ __align__(16) ushort Bs[128 * 32];
    const int t = threadIdx.x;
    const int2 bxy = xcd_swz(blockIdx.x, blockIdx.y, gridDim.x, gridDim.y);
    const int n0 = bxy.x * 128, m0 = bxy.y * 128;
    const int ln = t & 63, wv = t >> 6;
    const int ln15 = ln & 15, q8 = ln >> 4;
    const int mw = (wv & 1) * 64, nw = (wv >> 1) * 64;
    const int sr = ln >> 2, sk = (ln & 3) * 8;
    const bf16* gA = Ab + (size_t)(m0 + wv * 32 + sr) * K + sk;
    const bf16* gB = Wb + (size_t)(n0 + wv * 32 + sr) * K + sk;
    const size_t r16 = (size_t)16 * K;
    ushort* lA = &As[wv * 1024];
    ushort* lB = &Bs[wv * 1024];
    f32x4 acc[4][4] = {};
    for (int k0 = 0; k0 < K; k0 += 32) {
        gload16(gA + k0,       lA);
        gload16(gA + r16 + k0, lA + 512);
        gload16(gB + k0,       lB);
        gload16(gB + r16 + k0, lB + 512);
        __syncthreads();
        short8 a[4], b[4];
#pragma unroll
        for (int i = 0; i < 4; ++i)
            a[i] = *(const short8*)&As[(mw + i * 16 + ln15) * 32 + q8 * 8];
#pragma unroll
        for (int j = 0; j < 4; ++j)
            b[j] = *(const short8*)&Bs[(nw + j * 16 + ln15) * 32 + q8 * 8];
#pragma unroll
        for (int i = 0; i < 4; ++i)
#pragma unroll
            for (int j = 0; j < 4; ++j)
                acc[i][j] = __builtin_amdgcn_mfma_f32_16x16x32_bf16(a[i], b[j], acc[i][j], 0, 0, 0);
        __syncthreads();
    }
#pragma unroll
    for (int j = 0; j < 4; ++j) {
        const int n = n0 + nw + j * 16 + ln15;
        const float bv = dl(&bias[n]);
#pragma unroll
        for (int i = 0; i < 4; ++i) {
            const int mb = m0 + mw + i * 16 + q8 * 4;
#pragma unroll
            for (int r = 0; r < 4; ++r)
                dstore(&C[(size_t)(mb + r) * ldc + n], acc[i][j][r] + bv);
        }
    }
}

// ---------- per-(b,h) attention: MFMA + T14 early w16T load (round-13 proven) ----------
template <typename T>
__global__ __launch_bounds__(256) void k_attn(
        const bf16* __restrict__ qnT, const bf16* __restrict__ g16,
        const bf16* __restrict__ w16T, const T* __restrict__ temp,
        bf16* __restrict__ xo) {
    const int h = blockIdx.x, b = blockIdx.y;
    const int tid = threadIdx.x;
    const int ln = tid & 63, wv = tid >> 6;
    const int ln15 = ln & 15, q8 = ln >> 4;
    const int colbase = b * EMB + h * HDD;
    __shared__ __align__(16) ushort smem[16384];   // 32 KB
    char* sm = (char*)smem;

    short8 wreg[4];
#pragma unroll
    for (int it = 0; it < 4; ++it) {
        int u = tid + it * 256;
        int q = u >> 3, e0 = (u & 7) * 8;
        wreg[it] = *(const short8*)&w16T[(size_t)q * COLS + colbase + e0];
    }

#pragma unroll
    for (int it = 0; it < 4; ++it) {
        int u = tid + it * 256;
        int e = u >> 4, q0 = (u & 15) * 8;
        short8 s = *(const short8*)&g16[(size_t)(colbase + e) * 128 + q0];
        *(short8*)(sm + ((e * 256 + q0 * 2) ^ ((e & 7) << 4))) = s;
    }
#pragma unroll
    for (int it = 0; it < 4; ++it) {
        int u = tid + it * 256;
        int d = u >> 4, q0 = (u & 15) * 8;
        short8 s = *(const short8*)&qnT[(size_t)(colbase + d) * 128 + q0];
        *(short8*)(sm + 16384 + ((d * 256 + q0 * 2) ^ ((d & 7) << 4))) = s;
    }
    __syncthreads();

    const int drow = 16 * wv + ln15;
    f32x4 acc[4] = {};
#pragma unroll
    for (int ks = 0; ks < 4; ++ks) {
        short8 bfrag = *(const short8*)(sm + 16384 +
            ((drow * 256 + ks * 64 + q8 * 16) ^ ((drow & 7) << 4)));
#pragma unroll
        for (int i = 0; i < 4; ++i) {
            int erow = i * 16 + ln15;
            short8 afrag = *(const short8*)(sm +
                ((erow * 256 + ks * 64 + q8 * 16) ^ ((erow & 7) << 4)));
            acc[i] = __builtin_amdgcn_mfma_f32_16x16x32_bf16(afrag, bfrag, acc[i], 0, 0, 0);
        }
    }

    const float tv = dl(&temp[h]);
    float p[4][4];
    float mx = -1e30f;
#pragma unroll
    for (int i = 0; i < 4; ++i)
#pragma unroll
        for (int r = 0; r < 4; ++r) { p[i][r] = acc[i][r] * tv; mx = fmaxf(mx, p[i][r]); }
    mx = fmaxf(mx, __shfl_xor(mx, 16, 64));
    mx = fmaxf(mx, __shfl_xor(mx, 32, 64));
    float sum = 0.f;
#pragma unroll
    for (int i = 0; i < 4; ++i)
#pragma unroll
        for (int r = 0; r < 4; ++r) { p[i][r] = __expf(p[i][r] - mx); sum += p[i][r]; }
    sum += __shfl_xor(sum, 16, 64);
    sum += __shfl_xor(sum, 32, 64);
    const float rs = 1.f / sum;

    __syncthreads();

#pragma unroll
    for (int i = 0; i < 4; ++i) {
        shortv4 s4;
#pragma unroll
        for (int r = 0; r < 4; ++r) s4[r] = (short)f2bf(p[i][r] * rs);
        *(shortv4*)(sm + 16384 + drow * 144 + q8 * 8 + 32 * i) = s4;
    }
#pragma unroll
    for (int it = 0; it < 4; ++it) {
        int u = tid + it * 256;
        int q = u >> 3, e0 = (u & 7) * 8;
        *(short8*)(sm + ((q * 128 + e0 * 2) ^ ((q & 7) << 4))) = wreg[it];
    }
    __syncthreads();

    f32x4 o[7] = {};
#pragma unroll
    for (int ks = 0; ks < 2; ++ks) {
        short8 afrag = *(const short8*)(sm + 16384 + drow * 144 + ks * 64 + q8 * 16);
#pragma unroll
        for (int j = 0; j < 7; ++j) {
            int qrow = j * 16 + ln15;
            short8 bfrag = *(const short8*)(sm +
                ((qrow * 128 + ks * 64 + q8 * 16) ^ ((qrow & 7) << 4)));
            o[j] = __builtin_amdgcn_mfma_f32_16x16x32_bf16(afrag, bfrag, o[j], 0, 0, 0);
        }
    }
    const int dbase = h * HDD + 16 * wv + q8 * 4;
#pragma unroll
    for (int j = 0; j < 7; ++j) {
        int q = j * 16 + ln15;
        if (q < NQ) {
            shortv4 s4;
#pragma unroll
            for (int r = 0; r < 4; ++r) s4[r] = (short)f2bf(o[j][r]);
            *(shortv4*)&xo[(size_t)(q * BSZ + b) * EMB + dbase] = s4;
        }
    }
}

extern "C" void kernel_launch(void* const* d_in, const int* in_sizes, int n_in,
                              void* d_out, int out_size, void* d_ws, size_t ws_size,
                              hipStream_t stream) {
    char* ws = (char*)d_ws;
    bf16* qb16  = (bf16*)(ws + OFF_QB);
    bf16* kb16  = (bf16*)(ws + OFF_KB);
    bf16* vb16  = (bf16*)(ws + OFF_VB);
    bf16* wi16  = (bf16*)(ws + OFF_WI);
    bf16* qp16  = (bf16*)(ws + OFF_QP16);
    bf16* kp16  = (bf16*)(ws + OFF_KP16);
    bf16* vp16  = (bf16*)(ws + OFF_VP16);
    bf16* qmnT  = (bf16*)(ws + OFF_QMNT);
    bf16* xmnT  = (bf16*)(ws + OFF_XMNT);
    bf16* wo16  = (bf16*)(ws + OFF_WO);
    bf16* kpT   = (bf16*)(ws + OFF_KPT);
    bf16* vpT   = (bf16*)(ws + OFF_VPT);
    bf16* w16T  = (bf16*)(ws + OFF_W16T);
    bf16* qnT   = (bf16*)(ws + OFF_QNT);
    bf16* g16   = (bf16*)(ws + OFF_G16);
    bf16* xo16  = (bf16*)(ws + OFF_XO);

    // Host-side dtype detect: query = 9,830,400 elems; bf16 iff 19,660,800 bytes.
    const bool isbf = (in_sizes[0] == 19660800);

    if (isbf) {
        k_maps<bf16><<<352, 256, 0, stream>>>((const bf16*)d_in[8], qmnT,
                                              (const bf16*)d_in[9], xmnT);
        k_proj2<bf16><<<dim3(6, 494), 256, 0, stream>>>(
            (const bf16*)d_in[0], (const bf16*)d_in[1], (const bf16*)d_in[2],
            (const bf16*)d_in[3], qp16, kp16, vp16, (const bf16*)d_in[4]);
        k_trn2<<<3072, 256, 0, stream>>>(kp16, vp16, kpT, vpT);
        k_trn<NQ, 128, 1><<<COLS / 64, 256, 0, stream>>>(qp16, qnT);
        k_gw<<<dim3(1, 1536), 256, 0, stream>>>(kpT, vpT, qmnT, xmnT, g16, w16T);
        k_attn<bf16><<<dim3(NHD, BSZ), 256, 0, stream>>>(
            qnT, g16, w16T, (const bf16*)d_in[7], xo16);
        k_gemm_mfma<bf16, bf16><<<dim3(6, 100), 256, 0, stream>>>(
            xo16, (const bf16*)d_in[5], (bf16*)d_out, (const bf16*)d_in[6],
            M_Q, EMB, EMB, EMB);
    } else {
        k_maps<float><<<352, 256, 0, stream>>>((const float*)d_in[8], qmnT,
                                               (const float*)d_in[9], xmnT);
        // fused one-time conversions: wi | qb | kb | vb | wo
        k_cvt5<<<24864, 256, 0, stream>>>(
            (const float*)d_in[3], wi16,
            (const float*)d_in[0], qb16,
            (const float*)d_in[1], kb16,
            (const float*)d_in[2], vb16,
            (const float*)d_in[5], wo16);
        // minimal-barrier 256^2 fused projections: qp (50 tiles) | kp (99) | vp (99)
        k_mm8<bf16><<<dim3(3, 248), 512, 0, stream>>>(
            qb16, kb16, vb16, wi16, qp16, kp16, vp16,
            (const float*)d_in[4], 50, 149);
        // fused transposes: kpT(norm) + vpT
        k_trn2<<<3072, 256, 0, stream>>>(kp16, vp16, kpT, vpT);
        // qnT (kp16 dead; MUST run after k_trn2 — qnT aliases kp16)
        k_trn<NQ, 128, 1><<<COLS / 64, 256, 0, stream>>>(qp16, qnT);
        // fused mapper GEMMs: g16 + w16T
        k_gw<<<dim3(1, 1536), 256, 0, stream>>>(kpT, vpT, qmnT, xmnT, g16, w16T);
        // attention -> xo16 (kpT dead)
        k_attn<float><<<dim3(NHD, BSZ), 256, 0, stream>>>(
            qnT, g16, w16T, (const float*)d_in[7], xo16);
        // out = xo @ wout^T + bout via mm8 (M=12800 = 50x256 exact, N=768 = 3x256)
        k_mm8<float><<<dim3(3, 50), 512, 0, stream>>>(
            xo16, nullptr, nullptr, wo16, (float*)d_out, nullptr, nullptr,
            (const float*)d_in[6], 50, 50);
    }
}

// Round 17
// 449.218 us; speedup vs baseline: 1.0296x; 1.0114x over previous
//
#include <hip/hip_runtime.h>
#include <hip/hip_bf16.h>

using bf16 = __hip_bfloat16;

// Problem constants
constexpr int NQ  = 100;
constexpr int NT  = 197;
constexpr int BSZ = 128;
constexpr int EMB = 768;
constexpr int NHD = 12;
constexpr int HDD = 64;
constexpr int COLS = BSZ * EMB;          // 98304
constexpr int M_Q  = 12800;
constexpr int M_KV = 25216;
constexpr int M_KVP = 25344;             // padded to 99*256 for 256-row tiles
constexpr int TPAD = 224;

// ---- layout (lifetime-packed; 199.5MB < proven 218.4MB budget) ----
constexpr size_t SZ_Q16  = (size_t)M_Q  * EMB * 2;   // 19,660,800
constexpr size_t SZ_KV16 = (size_t)M_KV * EMB * 2;   // 38,731,776
constexpr size_t SZ_KVP  = (size_t)M_KVP * EMB * 2;  // 38,928,384
constexpr size_t SZ_WI   = (size_t)3 * EMB * EMB * 2;// 3,538,944
constexpr size_t SZ_T16  = (size_t)COLS * TPAD * 2;  // 44,040,192
constexpr size_t OFF_QB   = 256;
constexpr size_t OFF_KB   = OFF_QB + SZ_Q16;
constexpr size_t OFF_VB   = OFF_KB + SZ_KV16;
constexpr size_t OFF_WI   = OFF_VB + SZ_KV16;
constexpr size_t OFF_QP16 = OFF_WI + SZ_WI;
constexpr size_t OFF_KP16 = OFF_QP16 + SZ_Q16;
constexpr size_t OFF_VP16 = OFF_KP16 + SZ_KVP;
constexpr size_t OFF_QMNT = OFF_VP16 + SZ_KVP;
constexpr size_t OFF_XMNT = OFF_QMNT + 57344;
constexpr size_t OFF_WO   = OFF_XMNT + 57344;        // end 199,475,456
constexpr size_t OFF_KPT  = 256;                     // over qb+kb
constexpr size_t OFF_VPT  = OFF_KPT + SZ_T16;        // over kb-tail+vb
constexpr size_t OFF_W16T = OFF_VPT + SZ_T16;        // over wi+qp16
constexpr size_t OFF_QNT  = OFF_KP16;                // over kp16 (must run AFTER k_trn2)
constexpr size_t OFF_G16  = OFF_VP16;                // over vp16
constexpr size_t OFF_XO   = 256;                     // over kpT

__device__ __forceinline__ float dl(const float* p) { return *p; }
__device__ __forceinline__ float dl(const bf16* p) { return __bfloat162float(*p); }

__device__ __forceinline__ ushort f2bf(float x) {
    union { float f; unsigned u; } v; v.f = x;
    unsigned r = v.u + 0x7FFFu + ((v.u >> 16) & 1u);   // RNE
    return (ushort)(r >> 16);
}
__device__ __forceinline__ float bf2f(ushort x) {
    union { unsigned u; float f; } v; v.u = (unsigned)x << 16;
    return v.f;
}
__device__ __forceinline__ void dstore(float* p, float v) { *p = v; }
__device__ __forceinline__ void dstore(bf16* p, float v) { *p = __float2bfloat16(v); }

typedef __attribute__((ext_vector_type(8))) short short8;
typedef __attribute__((ext_vector_type(4))) short shortv4;
typedef __attribute__((ext_vector_type(4))) float f32x4;

__device__ __forceinline__ void gload16(const bf16* g, ushort* l) {
    __builtin_amdgcn_global_load_lds(
        (const __attribute__((address_space(1))) unsigned int*)g,
        (__attribute__((address_space(3))) unsigned int*)l, 16, 0, 0);
}

__device__ __forceinline__ int2 xcd_swz(int bx, int by, int gx, int gy) {
    const int nwg = gx * gy;
    const int L = by * gx + bx;
    const int q = nwg >> 3, r = nwg & 7;
    const int c = L & 7, i = L >> 3;
    const int wg = (c < r ? c * (q + 1) : r * (q + 1) + (c - r) * q) + i;
    return make_int2(wg % gx, wg / gx);
}

// ---------- fused 7-segment prep: f32->bf16 cvts + mapper normalizations ----------
// blocks [0,24864): 5 cvt segments (wi|qb|kb|vb|wo), 2048 f32/block.
// blocks [24864,25088): q_mapper col-norm -> qmnT row t (padded zero).
// blocks [25088,25216): x_mapper row-norm -> xmnT row q (padded zero).
// All routing block-uniform; barriers only inside mapper segments (whole block
// takes the same branch). Mapper outputs consumed by k_gw (4 dispatches later).
template <typename TM>
__global__ __launch_bounds__(256) void k_cvt5(
        const float* __restrict__ s0, bf16* __restrict__ d0,   // wi   864 blocks
        const float* __restrict__ s1, bf16* __restrict__ d1,   // qb   4800
        const float* __restrict__ s2, bf16* __restrict__ d2,   // kb   9456
        const float* __restrict__ s3, bf16* __restrict__ d3,   // vb   9456
        const float* __restrict__ s4, bf16* __restrict__ d4,   // wo   288
        const TM* __restrict__ qm, bf16* __restrict__ qmnT,    // 224 blocks
        const TM* __restrict__ xm, bf16* __restrict__ xmnT) {  // 128 blocks
    int bk = blockIdx.x;
    const int tid = threadIdx.x;
    if (bk >= 24864) {
        __shared__ float red[256];
        if (bk < 25088) {
            int t = bk - 24864;
            float v = (t < NT && tid < NQ) ? dl(&qm[t * NQ + tid]) : 0.f;
            if (tid < 128) red[tid] = v * v;
            __syncthreads();
            for (int s = 64; s > 0; s >>= 1) { if (tid < s) red[tid] += red[tid + s]; __syncthreads(); }
            float inv = 1.f / fmaxf(sqrtf(red[0]), 1e-12f);
            if (tid < 128)
                dstore(&qmnT[(size_t)tid * TPAD + t], (t < NT && tid < NQ) ? v * inv : 0.f);
        } else {
            int q = bk - 25088, t = tid;
            float v = (q < NQ && t < NT) ? dl(&xm[q * NT + t]) : 0.f;
            red[t] = v * v;
            __syncthreads();
            for (int s = 128; s > 0; s >>= 1) { if (t < s) red[t] += red[t + s]; __syncthreads(); }
            float inv = 1.f / fmaxf(sqrtf(red[0]), 1e-12f);
            if (t < TPAD) dstore(&xmnT[(size_t)q * TPAD + t], (q < NQ && t < NT) ? v * inv : 0.f);
        }
        return;
    }
    const float* s; bf16* d; int lb;
    if      (bk < 864)   { s = s0; d = d0; lb = bk; }
    else if (bk < 5664)  { s = s1; d = d1; lb = bk - 864; }
    else if (bk < 15120) { s = s2; d = d2; lb = bk - 5664; }
    else if (bk < 24576) { s = s3; d = d3; lb = bk - 15120; }
    else                 { s = s4; d = d4; lb = bk - 24576; }
    size_t i = ((size_t)lb * 256 + tid) * 8;
    float4 a = *(const float4*)(s + i), b = *(const float4*)(s + i + 4);
    short8 r;
    r[0] = (short)f2bf(a.x); r[1] = (short)f2bf(a.y); r[2] = (short)f2bf(a.z); r[3] = (short)f2bf(a.w);
    r[4] = (short)f2bf(b.x); r[5] = (short)f2bf(b.y); r[6] = (short)f2bf(b.z); r[7] = (short)f2bf(b.w);
    *(short8*)(d + i) = r;
}

// ---------- MERGED mapper normalizations (bf16 hedge path only) ----------
template <typename T>
__global__ __launch_bounds__(256) void k_maps(const T* __restrict__ qm, bf16* qmnT,
                                              const T* __restrict__ xm, bf16* xmnT) {
    __shared__ float red[256];
    const int bk = blockIdx.x, tid = threadIdx.x;
    if (bk < 224) {
        int t = bk;
        float v = (t < NT && tid < NQ) ? dl(&qm[t * NQ + tid]) : 0.f;
        if (tid < 128) red[tid] = v * v;
        __syncthreads();
        for (int s = 64; s > 0; s >>= 1) { if (tid < s) red[tid] += red[tid + s]; __syncthreads(); }
        float inv = 1.f / fmaxf(sqrtf(red[0]), 1e-12f);
        if (tid < 128)
            dstore(&qmnT[(size_t)tid * TPAD + t], (t < NT && tid < NQ) ? v * inv : 0.f);
    } else {
        int q = bk - 224, t = tid;
        float v = (q < NQ && t < NT) ? dl(&xm[q * NT + t]) : 0.f;
        red[t] = v * v;
        __syncthreads();
        for (int s = 128; s > 0; s >>= 1) { if (t < s) red[t] += red[t + s]; __syncthreads(); }
        float inv = 1.f / fmaxf(sqrtf(red[0]), 1e-12f);
        if (t < TPAD) dstore(&xmnT[(size_t)q * TPAD + t], (q < NQ && t < NT) ? v * inv : 0.f);
    }
}

// ---------- transpose (+ optional column L2-norm) ----------
template <int NR, int TP, int NORM>
__global__ __launch_bounds__(256) void k_trn(const bf16* __restrict__ src,
        bf16* __restrict__ dst) {
    __shared__ ushort tile[TP * 73];
    __shared__ float ssp[4][64];
    __shared__ float inv_s[64];
    const int col0 = blockIdx.x * 64;
    const int tid = threadIdx.x;
    const int c = tid & 63, tb = tid >> 6;
    float ss = 0.f;
#pragma unroll
    for (int it = 0; it < TP / 4; ++it) {
        int t = tb + it * 4;
        ushort v = 0;
        if (t < NR) v = *(const ushort*)&src[(size_t)t * COLS + col0 + c];
        tile[t * 73 + c] = v;
        if (NORM) { float f = bf2f(v); ss = fmaf(f, f, ss); }
    }
    if (NORM) {
        ssp[tb][c] = ss;
        __syncthreads();
        if (tid < 64) {
            float s = ssp[0][tid] + ssp[1][tid] + ssp[2][tid] + ssp[3][tid];
            inv_s[tid] = 1.f / fmaxf(sqrtf(s), 1e-12f);
        }
    }
    __syncthreads();
    constexpr int UPC = TP / 8;
#pragma unroll
    for (int it = 0; it < (64 * UPC) / 256; ++it) {
        int u = tid + it * 256;
        int cc = u / UPC, t0 = (u % UPC) * 8;
        float inv = NORM ? inv_s[cc] : 1.f;
        short8 s;
#pragma unroll
        for (int r = 0; r < 8; ++r) {
            ushort raw = tile[(t0 + r) * 73 + cc];
            s[r] = NORM ? (short)f2bf(bf2f(raw) * inv) : (short)raw;
        }
        *(short8*)&dst[(size_t)(col0 + cc) * TP + t0] = s;
    }
}

// ---------- fused dual transpose: kp16->kpT16(norm) + vp16->vpT16(plain) ----------
__global__ __launch_bounds__(256) void k_trn2(const bf16* __restrict__ kp,
        const bf16* __restrict__ vp, bf16* __restrict__ kpT, bf16* __restrict__ vpT) {
    __shared__ ushort tile[TPAD * 73];
    __shared__ float ssp[4][64];
    __shared__ float inv_s[64];
    const int bk = blockIdx.x;
    const bool vseg = bk >= 1536;
    const bf16* src = vseg ? vp : kp;
    bf16* dst = vseg ? vpT : kpT;
    const int col0 = (vseg ? bk - 1536 : bk) * 64;
    const int tid = threadIdx.x;
    const int c = tid & 63, tb = tid >> 6;
    float ss = 0.f;
#pragma unroll
    for (int it = 0; it < TPAD / 4; ++it) {
        int t = tb + it * 4;
        ushort v = 0;
        if (t < NT) v = *(const ushort*)&src[(size_t)t * COLS + col0 + c];
        tile[t * 73 + c] = v;
        if (!vseg) { float f = bf2f(v); ss = fmaf(f, f, ss); }
    }
    if (!vseg) {
        ssp[tb][c] = ss;
        __syncthreads();
        if (tid < 64) {
            float s = ssp[0][tid] + ssp[1][tid] + ssp[2][tid] + ssp[3][tid];
            inv_s[tid] = 1.f / fmaxf(sqrtf(s), 1e-12f);
        }
    }
    __syncthreads();
    constexpr int UPC = TPAD / 8;                 // 28
#pragma unroll
    for (int it = 0; it < (64 * UPC) / 256; ++it) {   // 7
        int u = tid + it * 256;
        int cc = u / UPC, t0 = (u % UPC) * 8;
        float inv = vseg ? 1.f : inv_s[cc];
        short8 s;
#pragma unroll
        for (int r = 0; r < 8; ++r) {
            ushort raw = tile[(t0 + r) * 73 + cc];
            s[r] = vseg ? (short)raw : (short)f2bf(bf2f(raw) * inv);
        }
        *(short8*)&dst[(size_t)(col0 + cc) * TPAD + t0] = s;
    }
}

// ===== 256x256 MFMA GEMM: T2-swizzled, minimal-barrier (round-14/16 proven) ====
#define MM8_BAR  { __builtin_amdgcn_s_barrier(); __builtin_amdgcn_sched_barrier(0); }
#define MM8_LGK0 { asm volatile("s_waitcnt lgkmcnt(0)" ::: "memory"); __builtin_amdgcn_sched_barrier(0); }
#define MM8_VM8  { asm volatile("s_waitcnt vmcnt(8)" ::: "memory"); __builtin_amdgcn_sched_barrier(0); }
#define MM8_VM0  { asm volatile("s_waitcnt vmcnt(0)" ::: "memory"); __builtin_amdgcn_sched_barrier(0); }
#define MM8_STAGE(CUR, ISB, H, KT) do { \
    const bf16* gb_ = (ISB) ? (Wb + (size_t)(n0 + (H)*128 + srow) * EMB + (KT)*64 + sk_sw) \
                            : (Ab + (size_t)(m0 + (H)*128 + srow) * EMB + (KT)*64 + sk_sw); \
    ushort* lb_ = ((ISB) ? B_lds : A_lds) + (CUR)*16384 + (H)*8192 + wid*512; \
    gload16(gb_, lb_); \
    gload16(gb_ + (size_t)64 * EMB, lb_ + 4096); \
} while (0)
#define MM8_LOADFRAGS(CUR, KK, AARR, BARR) { \
    _Pragma("unroll") for (int m_ = 0; m_ < 8; ++m_) { \
        int ra_ = wr*128 + m_*16 + ln15; \
        AARR[m_] = *(const short8*)&A_lds[(CUR)*16384 + ra_*64 + ((((KK)*4 + q8) ^ (ra_ & 7)))*8]; } \
    _Pragma("unroll") for (int j_ = 0; j_ < 4; ++j_) { \
        int rb_ = wc*64 + j_*16 + ln15; \
        BARR[j_] = *(const short8*)&B_lds[(CUR)*16384 + rb_*64 + ((((KK)*4 + q8) ^ (rb_ & 7)))*8]; } }
#define MM8_QUAD(AARR, BARR, MB) { \
    __builtin_amdgcn_s_setprio(1); \
    _Pragma("unroll") for (int m_ = 0; m_ < 4; ++m_) \
        _Pragma("unroll") for (int j_ = 0; j_ < 4; ++j_) \
            acc[(MB) + m_][j_] = __builtin_amdgcn_mfma_f32_16x16x32_bf16( \
                AARR[(MB) + m_], BARR[j_], acc[(MB) + m_][j_], 0, 0, 0); \
    __builtin_amdgcn_s_setprio(0); }

template <typename TC>
__global__ __launch_bounds__(512, 2) void k_mm8(
        const bf16* __restrict__ A0, const bf16* __restrict__ A1, const bf16* __restrict__ A2,
        const bf16* __restrict__ W,
        TC* __restrict__ C0, TC* __restrict__ C1, TC* __restrict__ C2,
        const float* __restrict__ bias, int mt0, int mt01) {
    __shared__ __align__(16) ushort A_lds[2 * 16384];   // 64KB
    __shared__ __align__(16) ushort B_lds[2 * 16384];   // 64KB
    const int tid = threadIdx.x;
    const int2 bxy = xcd_swz(blockIdx.x, blockIdx.y, gridDim.x, gridDim.y);
    int seg = 0, lby = bxy.y;
    if (bxy.y < mt0)       { seg = 0; lby = bxy.y; }
    else if (bxy.y < mt01) { seg = 1; lby = bxy.y - mt0; }
    else                   { seg = 2; lby = bxy.y - mt01; }
    const bf16* Ab = seg == 0 ? A0 : (seg == 1 ? A1 : A2);
    const bf16* Wb = W + (size_t)seg * EMB * EMB;
    TC* C = seg == 0 ? C0 : (seg == 1 ? C1 : C2);
    const float* bp = bias + seg * EMB;
    const int m0 = lby * 256, n0 = bxy.x * 256;
    const int wid = tid >> 6, ln = tid & 63;
    const int wr = wid >> 2, wc = wid & 3;
    const int ln15 = ln & 15, q8 = ln >> 4;
    const int srow = tid >> 3;
    const int sk_sw = (((tid & 7) ^ (srow & 7)) * 8);   // T2 pre-swizzled source col

    f32x4 acc[8][4] = {};
    short8 a0[8], b0[4], a1[8], b1[4];

    // prologue: tile0 + tile1 staged; tile0 published
    MM8_STAGE(0, 0, 0, 0); MM8_STAGE(0, 0, 1, 0); MM8_STAGE(0, 1, 0, 0); MM8_STAGE(0, 1, 1, 0);
    MM8_STAGE(1, 0, 0, 1); MM8_STAGE(1, 0, 1, 1); MM8_STAGE(1, 1, 0, 1); MM8_STAGE(1, 1, 1, 1);
    MM8_VM8;
    MM8_BAR;

    // main loop: 12 K-tiles, 2 barriers per tile (E1, E2)
    for (int t = 0; t < 12; ++t) {
        const int c = t & 1, nxt = t + 2;
        MM8_LOADFRAGS(c, 0, a0, b0);
        MM8_QUAD(a0, b0, 0);
        MM8_LOADFRAGS(c, 1, a1, b1);
        MM8_QUAD(a0, b0, 4);
        MM8_LGK0;                 // all reads of buf c serviced for this wave
        MM8_BAR;                  // E1: ... for ALL waves -> restage safe
        if (nxt < 12) { MM8_STAGE(c, 0, 0, nxt); MM8_STAGE(c, 0, 1, nxt); }
        MM8_QUAD(a1, b1, 0);
        if (nxt < 12) { MM8_STAGE(c, 1, 0, nxt); MM8_STAGE(c, 1, 1, nxt); }
        if (t < 10) { MM8_VM8; } else { MM8_VM0; }   // own t+1 loads landed
        MM8_QUAD(a1, b1, 4);
        MM8_BAR;                  // E2: t+1 published for all waves
    }

    // epilogue: C-write with bias
#pragma unroll
    for (int j = 0; j < 4; ++j) {
        const int n = n0 + wc * 64 + j * 16 + ln15;
        const float bv = bp[n];
#pragma unroll
        for (int m = 0; m < 8; ++m) {
            const int mb = m0 + wr * 128 + m * 16 + q8 * 4;
#pragma unroll
            for (int r = 0; r < 4; ++r)
                dstore(&C[(size_t)(mb + r) * EMB + n], acc[m][j][r] + bv);
        }
    }
}

// ---------- 2-phase fused projection (bf16 hedge path; round-9 proven) ----------
template <typename TBias>
__global__ __launch_bounds__(256) void k_proj2(
        const bf16* __restrict__ Aq, const bf16* __restrict__ Ak, const bf16* __restrict__ Av,
        const bf16* __restrict__ Wi, bf16* __restrict__ Cq, bf16* __restrict__ Ck,
        bf16* __restrict__ Cv, const TBias* __restrict__ bias) {
    __shared__ __align__(16) ushort As[128 * 32];
    __shared__ __align__(16) ushort Bs[128 * 32];
    const int t = threadIdx.x;
    const int2 bxy = xcd_swz(blockIdx.x, blockIdx.y, gridDim.x, gridDim.y);
    int byy = bxy.y, seg, lby;
    if (byy < 100)      { seg = 0; lby = byy; }
    else if (byy < 297) { seg = 1; lby = byy - 100; }
    else                { seg = 2; lby = byy - 297; }
    const bf16* Ab = seg == 0 ? Aq : (seg == 1 ? Ak : Av);
    const bf16* Wb = Wi + (size_t)seg * EMB * EMB;
    bf16* C = seg == 0 ? Cq : (seg == 1 ? Ck : Cv);
    const TBias* bp = bias + seg * EMB;
    const int n0 = bxy.x * 128, m0 = lby * 128;
    const int ln = t & 63, wv = t >> 6;
    const int ln15 = ln & 15, q8 = ln >> 4;
    const int mw = (wv & 1) * 64, nw = (wv >> 1) * 64;
    const int sr = ln >> 2, sk = (ln & 3) * 8;
    const bf16* gA = Ab + (size_t)(m0 + wv * 32 + sr) * EMB + sk;
    const bf16* gB = Wb + (size_t)(n0 + wv * 32 + sr) * EMB + sk;
    const size_t r16 = (size_t)16 * EMB;
    ushort* lA = &As[wv * 1024];
    ushort* lB = &Bs[wv * 1024];
    f32x4 acc[4][4] = {};
    for (int k0 = 0; k0 < EMB; k0 += 32) {
        gload16(gA + k0,       lA);
        gload16(gA + r16 + k0, lA + 512);
        gload16(gB + k0,       lB);
        gload16(gB + r16 + k0, lB + 512);
        __syncthreads();
        short8 a[4], b[4];
#pragma unroll
        for (int i = 0; i < 4; ++i)
            a[i] = *(const short8*)&As[(mw + i * 16 + ln15) * 32 + q8 * 8];
#pragma unroll
        for (int j = 0; j < 4; ++j)
            b[j] = *(const short8*)&Bs[(nw + j * 16 + ln15) * 32 + q8 * 8];
#pragma unroll
        for (int i = 0; i < 4; ++i)
#pragma unroll
            for (int j = 0; j < 4; ++j)
                acc[i][j] = __builtin_amdgcn_mfma_f32_16x16x32_bf16(a[i], b[j], acc[i][j], 0, 0, 0);
        __syncthreads();
    }
#pragma unroll
    for (int j = 0; j < 4; ++j) {
        const int n = n0 + nw + j * 16 + ln15;
        const float bv = dl(&bp[n]);
#pragma unroll
        for (int i = 0; i < 4; ++i) {
            const int mb = m0 + mw + i * 16 + q8 * 4;
#pragma unroll
            for (int r = 0; r < 4; ++r)
                dstore(&C[(size_t)(mb + r) * EMB + n], acc[i][j][r] + bv);
        }
    }
}

// ---------- FUSED mapper GEMM: g16 | w16T (K=224; round-9 proven) ----------
__global__ __launch_bounds__(256) void k_gw(
        const bf16* __restrict__ kpT, const bf16* __restrict__ vpT,
        const bf16* __restrict__ qmnT, const bf16* __restrict__ xmnT,
        bf16* __restrict__ g16, bf16* __restrict__ w16T) {
    __shared__ __align__(16) ushort As[128 * 32];
    __shared__ __align__(16) ushort Bs[128 * 32];
    const int t = threadIdx.x;
    const int2 bxy = xcd_swz(blockIdx.x, blockIdx.y, gridDim.x, gridDim.y);
    const bool wseg = bxy.y >= 768;
    const int lby = wseg ? bxy.y - 768 : bxy.y;
    const bf16* Ab = wseg ? vpT : kpT;
    const bf16* Bb = wseg ? xmnT : qmnT;
    const int m0 = lby * 128;
    const int ln = t & 63, wv = t >> 6;
    const int ln15 = ln & 15, q8 = ln >> 4;
    const int mw = (wv & 1) * 64, nw = (wv >> 1) * 64;
    const int sr = ln >> 2, sk = (ln & 3) * 8;
    const bf16* gA = Ab + (size_t)(m0 + wv * 32 + sr) * TPAD + sk;
    const bf16* gB = Bb + (size_t)(wv * 32 + sr) * TPAD + sk;
    const size_t r16 = (size_t)16 * TPAD;
    ushort* lA = &As[wv * 1024];
    ushort* lB = &Bs[wv * 1024];
    f32x4 acc[4][4] = {};
    for (int k0 = 0; k0 < TPAD; k0 += 32) {
        gload16(gA + k0,       lA);
        gload16(gA + r16 + k0, lA + 512);
        gload16(gB + k0,       lB);
        gload16(gB + r16 + k0, lB + 512);
        __syncthreads();
        short8 a[4], b[4];
#pragma unroll
        for (int i = 0; i < 4; ++i)
            a[i] = *(const short8*)&As[(mw + i * 16 + ln15) * 32 + q8 * 8];
#pragma unroll
        for (int j = 0; j < 4; ++j)
            b[j] = *(const short8*)&Bs[(nw + j * 16 + ln15) * 32 + q8 * 8];
#pragma unroll
        for (int i = 0; i < 4; ++i)
#pragma unroll
            for (int j = 0; j < 4; ++j)
                acc[i][j] = __builtin_amdgcn_mfma_f32_16x16x32_bf16(a[i], b[j], acc[i][j], 0, 0, 0);
        __syncthreads();
    }
#pragma unroll
    for (int j = 0; j < 4; ++j) {
        const int n = nw + j * 16 + ln15;
#pragma unroll
        for (int i = 0; i < 4; ++i) {
            const int mb = m0 + mw + i * 16 + q8 * 4;
            if (wseg) {
                shortv4 s;
#pragma unroll
                for (int r = 0; r < 4; ++r) s[r] = (short)f2bf(acc[i][j][r]);
                *(shortv4*)&w16T[(size_t)n * COLS + mb] = s;
            } else {
#pragma unroll
                for (int r = 0; r < 4; ++r)
                    dstore(&g16[(size_t)(mb + r) * 128 + n], acc[i][j][r]);
            }
        }
    }
}

// ---------- MFMA bf16 GEMM (bf16-path out-projection; round-8 proven) ----------
template <typename TC, typename TBias>
__global__ __launch_bounds__(256) void k_gemm_mfma(
        const bf16* __restrict__ Ab, const bf16* __restrict__ Wb,
        TC* __restrict__ C, const TBias* __restrict__ bias,
        int M, int N, int K, int ldc) {
    __shared__ __align__(16) ushort As[128 * 32];
    __shared__ __align__(16) ushort Bs[128 * 32];
    const int t = threadIdx.x;
    const int2 bxy = xcd_swz(blockIdx.x, blockIdx.y, gridDim.x, gridDim.y);
    const int n0 = bxy.x * 128, m0 = bxy.y * 128;
    const int ln = t & 63, wv = t >> 6;
    const int ln15 = ln & 15, q8 = ln >> 4;
    const int mw = (wv & 1) * 64, nw = (wv >> 1) * 64;
    const int sr = ln >> 2, sk = (ln & 3) * 8;
    const bf16* gA = Ab + (size_t)(m0 + wv * 32 + sr) * K + sk;
    const bf16* gB = Wb + (size_t)(n0 + wv * 32 + sr) * K + sk;
    const size_t r16 = (size_t)16 * K;
    ushort* lA = &As[wv * 1024];
    ushort* lB = &Bs[wv * 1024];
    f32x4 acc[4][4] = {};
    for (int k0 = 0; k0 < K; k0 += 32) {
        gload16(gA + k0,       lA);
        gload16(gA + r16 + k0, lA + 512);
        gload16(gB + k0,       lB);
        gload16(gB + r16 + k0, lB + 512);
        __syncthreads();
        short8 a[4], b[4];
#pragma unroll
        for (int i = 0; i < 4; ++i)
            a[i] = *(const short8*)&As[(mw + i * 16 + ln15) * 32 + q8 * 8];
#pragma unroll
        for (int j = 0; j < 4; ++j)
            b[j] = *(const short8*)&Bs[(nw + j * 16 + ln15) * 32 + q8 * 8];
#pragma unroll
        for (int i = 0; i < 4; ++i)
#pragma unroll
            for (int j = 0; j < 4; ++j)
                acc[i][j] = __builtin_amdgcn_mfma_f32_16x16x32_bf16(a[i], b[j], acc[i][j], 0, 0, 0);
        __syncthreads();
    }
#pragma unroll
    for (int j = 0; j < 4; ++j) {
        const int n = n0 + nw + j * 16 + ln15;
        const float bv = dl(&bias[n]);
#pragma unroll
        for (int i = 0; i < 4; ++i) {
            const int mb = m0 + mw + i * 16 + q8 * 4;
#pragma unroll
            for (int r = 0; r < 4; ++r)
                dstore(&C[(size_t)(mb + r) * ldc + n], acc[i][j][r] + bv);
        }
    }
}

// ---------- per-(b,h) attention: MFMA + T14 early w16T load (round-13 proven) ----------
template <typename T>
__global__ __launch_bounds__(256) void k_attn(
        const bf16* __restrict__ qnT, const bf16* __restrict__ g16,
        const bf16* __restrict__ w16T, const T* __restrict__ temp,
        bf16* __restrict__ xo) {
    const int h = blockIdx.x, b = blockIdx.y;
    const int tid = threadIdx.x;
    const int ln = tid & 63, wv = tid >> 6;
    const int ln15 = ln & 15, q8 = ln >> 4;
    const int colbase = b * EMB + h * HDD;
    __shared__ __align__(16) ushort smem[16384];   // 32 KB
    char* sm = (char*)smem;

    short8 wreg[4];
#pragma unroll
    for (int it = 0; it < 4; ++it) {
        int u = tid + it * 256;
        int q = u >> 3, e0 = (u & 7) * 8;
        wreg[it] = *(const short8*)&w16T[(size_t)q * COLS + colbase + e0];
    }

#pragma unroll
    for (int it = 0; it < 4; ++it) {
        int u = tid + it * 256;
        int e = u >> 4, q0 = (u & 15) * 8;
        short8 s = *(const short8*)&g16[(size_t)(colbase + e) * 128 + q0];
        *(short8*)(sm + ((e * 256 + q0 * 2) ^ ((e & 7) << 4))) = s;
    }
#pragma unroll
    for (int it = 0; it < 4; ++it) {
        int u = tid + it * 256;
        int d = u >> 4, q0 = (u & 15) * 8;
        short8 s = *(const short8*)&qnT[(size_t)(colbase + d) * 128 + q0];
        *(short8*)(sm + 16384 + ((d * 256 + q0 * 2) ^ ((d & 7) << 4))) = s;
    }
    __syncthreads();

    const int drow = 16 * wv + ln15;
    f32x4 acc[4] = {};
#pragma unroll
    for (int ks = 0; ks < 4; ++ks) {
        short8 bfrag = *(const short8*)(sm + 16384 +
            ((drow * 256 + ks * 64 + q8 * 16) ^ ((drow & 7) << 4)));
#pragma unroll
        for (int i = 0; i < 4; ++i) {
            int erow = i * 16 + ln15;
            short8 afrag = *(const short8*)(sm +
                ((erow * 256 + ks * 64 + q8 * 16) ^ ((erow & 7) << 4)));
            acc[i] = __builtin_amdgcn_mfma_f32_16x16x32_bf16(afrag, bfrag, acc[i], 0, 0, 0);
        }
    }

    const float tv = dl(&temp[h]);
    float p[4][4];
    float mx = -1e30f;
#pragma unroll
    for (int i = 0; i < 4; ++i)
#pragma unroll
        for (int r = 0; r < 4; ++r) { p[i][r] = acc[i][r] * tv; mx = fmaxf(mx, p[i][r]); }
    mx = fmaxf(mx, __shfl_xor(mx, 16, 64));
    mx = fmaxf(mx, __shfl_xor(mx, 32, 64));
    float sum = 0.f;
#pragma unroll
    for (int i = 0; i < 4; ++i)
#pragma unroll
        for (int r = 0; r < 4; ++r) { p[i][r] = __expf(p[i][r] - mx); sum += p[i][r]; }
    sum += __shfl_xor(sum, 16, 64);
    sum += __shfl_xor(sum, 32, 64);
    const float rs = 1.f / sum;

    __syncthreads();

#pragma unroll
    for (int i = 0; i < 4; ++i) {
        shortv4 s4;
#pragma unroll
        for (int r = 0; r < 4; ++r) s4[r] = (short)f2bf(p[i][r] * rs);
        *(shortv4*)(sm + 16384 + drow * 144 + q8 * 8 + 32 * i) = s4;
    }
#pragma unroll
    for (int it = 0; it < 4; ++it) {
        int u = tid + it * 256;
        int q = u >> 3, e0 = (u & 7) * 8;
        *(short8*)(sm + ((q * 128 + e0 * 2) ^ ((q & 7) << 4))) = wreg[it];
    }
    __syncthreads();

    f32x4 o[7] = {};
#pragma unroll
    for (int ks = 0; ks < 2; ++ks) {
        short8 afrag = *(const short8*)(sm + 16384 + drow * 144 + ks * 64 + q8 * 16);
#pragma unroll
        for (int j = 0; j < 7; ++j) {
            int qrow = j * 16 + ln15;
            short8 bfrag = *(const short8*)(sm +
                ((qrow * 128 + ks * 64 + q8 * 16) ^ ((qrow & 7) << 4)));
            o[j] = __builtin_amdgcn_mfma_f32_16x16x32_bf16(afrag, bfrag, o[j], 0, 0, 0);
        }
    }
    const int dbase = h * HDD + 16 * wv + q8 * 4;
#pragma unroll
    for (int j = 0; j < 7; ++j) {
        int q = j * 16 + ln15;
        if (q < NQ) {
            shortv4 s4;
#pragma unroll
            for (int r = 0; r < 4; ++r) s4[r] = (short)f2bf(o[j][r]);
            *(shortv4*)&xo[(size_t)(q * BSZ + b) * EMB + dbase] = s4;
        }
    }
}

extern "C" void kernel_launch(void* const* d_in, const int* in_sizes, int n_in,
                              void* d_out, int out_size, void* d_ws, size_t ws_size,
                              hipStream_t stream) {
    char* ws = (char*)d_ws;
    bf16* qb16  = (bf16*)(ws + OFF_QB);
    bf16* kb16  = (bf16*)(ws + OFF_KB);
    bf16* vb16  = (bf16*)(ws + OFF_VB);
    bf16* wi16  = (bf16*)(ws + OFF_WI);
    bf16* qp16  = (bf16*)(ws + OFF_QP16);
    bf16* kp16  = (bf16*)(ws + OFF_KP16);
    bf16* vp16  = (bf16*)(ws + OFF_VP16);
    bf16* qmnT  = (bf16*)(ws + OFF_QMNT);
    bf16* xmnT  = (bf16*)(ws + OFF_XMNT);
    bf16* wo16  = (bf16*)(ws + OFF_WO);
    bf16* kpT   = (bf16*)(ws + OFF_KPT);
    bf16* vpT   = (bf16*)(ws + OFF_VPT);
    bf16* w16T  = (bf16*)(ws + OFF_W16T);
    bf16* qnT   = (bf16*)(ws + OFF_QNT);
    bf16* g16   = (bf16*)(ws + OFF_G16);
    bf16* xo16  = (bf16*)(ws + OFF_XO);

    // Host-side dtype detect: query = 9,830,400 elems; bf16 iff 19,660,800 bytes.
    const bool isbf = (in_sizes[0] == 19660800);

    if (isbf) {
        k_maps<bf16><<<352, 256, 0, stream>>>((const bf16*)d_in[8], qmnT,
                                              (const bf16*)d_in[9], xmnT);
        k_proj2<bf16><<<dim3(6, 494), 256, 0, stream>>>(
            (const bf16*)d_in[0], (const bf16*)d_in[1], (const bf16*)d_in[2],
            (const bf16*)d_in[3], qp16, kp16, vp16, (const bf16*)d_in[4]);
        k_trn2<<<3072, 256, 0, stream>>>(kp16, vp16, kpT, vpT);
        k_trn<NQ, 128, 1><<<COLS / 64, 256, 0, stream>>>(qp16, qnT);
        k_gw<<<dim3(1, 1536), 256, 0, stream>>>(kpT, vpT, qmnT, xmnT, g16, w16T);
        k_attn<bf16><<<dim3(NHD, BSZ), 256, 0, stream>>>(
            qnT, g16, w16T, (const bf16*)d_in[7], xo16);
        k_gemm_mfma<bf16, bf16><<<dim3(6, 100), 256, 0, stream>>>(
            xo16, (const bf16*)d_in[5], (bf16*)d_out, (const bf16*)d_in[6],
            M_Q, EMB, EMB, EMB);
    } else {
        // fused prep: cvts (wi|qb|kb|vb|wo) + mapper normalizations, ONE dispatch
        k_cvt5<float><<<25216, 256, 0, stream>>>(
            (const float*)d_in[3], wi16,
            (const float*)d_in[0], qb16,
            (const float*)d_in[1], kb16,
            (const float*)d_in[2], vb16,
            (const float*)d_in[5], wo16,
            (const float*)d_in[8], qmnT,
            (const float*)d_in[9], xmnT);
        // minimal-barrier 256^2 fused projections: qp (50 tiles) | kp (99) | vp (99)
        k_mm8<bf16><<<dim3(3, 248), 512, 0, stream>>>(
            qb16, kb16, vb16, wi16, qp16, kp16, vp16,
            (const float*)d_in[4], 50, 149);
        // fused transposes: kpT(norm) + vpT
        k_trn2<<<3072, 256, 0, stream>>>(kp16, vp16, kpT, vpT);
        // qnT (kp16 dead; MUST run after k_trn2 — qnT aliases kp16)
        k_trn<NQ, 128, 1><<<COLS / 64, 256, 0, stream>>>(qp16, qnT);
        // fused mapper GEMMs: g16 + w16T
        k_gw<<<dim3(1, 1536), 256, 0, stream>>>(kpT, vpT, qmnT, xmnT, g16, w16T);
        // attention -> xo16 (kpT dead)
        k_attn<float><<<dim3(NHD, BSZ), 256, 0, stream>>>(
            qnT, g16, w16T, (const float*)d_in[7], xo16);
        // out = xo @ wout^T + bout via mm8 (M=12800 = 50x256 exact, N=768 = 3x256)
        k_mm8<float><<<dim3(3, 50), 512, 0, stream>>>(
            xo16, nullptr, nullptr, wo16, (float*)d_out, nullptr, nullptr,
            (const float*)d_in[6], 50, 50);
    }
}